// Round 1
// baseline (4750.016 us; speedup 1.0000x reference)
//
#include <hip/hip_runtime.h>
#include <math.h>

#define D_MODEL 512
#define SEQ     1024
#define BATCH   4
#define N_LAYERS 2
#define N_HEAD  8
#define D_HEAD  64
#define D_INNER 1024
#define NTOK    (BATCH*SEQ)   // 4096
#define LN_EPS  1e-3f

// ---------------------------------------------------------------- add pos enc
__global__ void add_pos_kernel(const float* __restrict__ x,
                               const float* __restrict__ pe,
                               float* __restrict__ X) {
    int idx = blockIdx.x * blockDim.x + threadIdx.x;   // over NTOK*D_MODEL
    int l = (idx / D_MODEL) % SEQ;
    int d = idx % D_MODEL;
    X[idx] = x[idx] + pe[l * D_MODEL + d];
}

// ---------------------------------------------------------------- QKV proj
// grid: (NTOK/4, N_HEAD, 3), block: 64
// Q/K/V layout: [h][b*SEQ + l][dk]
__global__ void qkv_proj_kernel(const float* __restrict__ X,
                                const float* __restrict__ Wq,
                                const float* __restrict__ Wk,
                                const float* __restrict__ Wv,
                                float* __restrict__ Q,
                                float* __restrict__ Kb,
                                float* __restrict__ Vb) {
    int tok0 = blockIdx.x * 4;
    int h    = blockIdx.y;
    int which = blockIdx.z;
    const float* W = (which == 0) ? Wq : (which == 1) ? Wk : Wv;
    float*       O = (which == 0) ? Q  : (which == 1) ? Kb : Vb;

    __shared__ float xs[4][D_MODEL];
    const float* xg = X + (size_t)tok0 * D_MODEL;
    for (int idx = threadIdx.x; idx < 4 * D_MODEL; idx += 64)
        ((float*)xs)[idx] = xg[idx];
    __syncthreads();

    const float* Wh = W + (size_t)h * D_MODEL * D_HEAD;
    int t = threadIdx.x;
    float a0 = 0.f, a1 = 0.f, a2 = 0.f, a3 = 0.f;
    for (int d = 0; d < D_MODEL; d++) {
        float w = Wh[d * D_HEAD + t];
        a0 += xs[0][d] * w;
        a1 += xs[1][d] * w;
        a2 += xs[2][d] * w;
        a3 += xs[3][d] * w;
    }
    float* Oh = O + ((size_t)h * NTOK + tok0) * D_HEAD + t;
    Oh[0 * D_HEAD] = a0;
    Oh[1 * D_HEAD] = a1;
    Oh[2 * D_HEAD] = a2;
    Oh[3 * D_HEAD] = a3;
}

// ---------------------------------------------------------------- attention
// grid: (SEQ, BATCH, N_HEAD), block: 256
// O written directly in [b][l][h*64+t] (head-concat) layout.
__global__ void attention_kernel(const float* __restrict__ Q,
                                 const float* __restrict__ K,
                                 const float* __restrict__ V,
                                 float* __restrict__ O) {
    int row = blockIdx.x, b = blockIdx.y, h = blockIdx.z;
    int tid = threadIdx.x;
    __shared__ float sc[SEQ];
    __shared__ float qs[D_HEAD];
    __shared__ float tm[4], ts[4];
    __shared__ float op[4][D_HEAD];

    const int hb = h * BATCH + b;
    const float* qrow = Q + ((size_t)hb * SEQ + row) * D_HEAD;
    if (tid < D_HEAD) qs[tid] = qrow[tid];
    __syncthreads();

    const float inv_temper = 0.04419417382415922f;  // 1/sqrt(512)
    const float* Kp = K + (size_t)hb * SEQ * D_HEAD;
    float lmax = -1e30f;
    for (int m = tid; m < SEQ; m += 256) {
        const float4* kr = (const float4*)(Kp + (size_t)m * D_HEAD);
        float acc = 0.f;
#pragma unroll
        for (int j = 0; j < 16; j++) {
            float4 kv = kr[j];
            acc += kv.x * qs[4*j+0] + kv.y * qs[4*j+1]
                 + kv.z * qs[4*j+2] + kv.w * qs[4*j+3];
        }
        acc *= inv_temper;
        sc[m] = acc;
        lmax = fmaxf(lmax, acc);
    }
    // block max (4 waves)
#pragma unroll
    for (int off = 32; off > 0; off >>= 1)
        lmax = fmaxf(lmax, __shfl_down(lmax, off, 64));
    if ((tid & 63) == 0) tm[tid >> 6] = lmax;
    __syncthreads();
    float gmax = fmaxf(fmaxf(tm[0], tm[1]), fmaxf(tm[2], tm[3]));

    float lsum = 0.f;
    for (int m = tid; m < SEQ; m += 256) {
        float p = __expf(sc[m] - gmax);
        sc[m] = p;
        lsum += p;
    }
#pragma unroll
    for (int off = 32; off > 0; off >>= 1)
        lsum += __shfl_down(lsum, off, 64);
    if ((tid & 63) == 0) ts[tid >> 6] = lsum;
    __syncthreads();   // also makes all sc[] writes visible
    float gsum = ts[0] + ts[1] + ts[2] + ts[3];

    int g = tid >> 6, t = tid & 63;
    const float* Vp = V + (size_t)hb * SEQ * D_HEAD;
    float acc = 0.f;
    for (int m = g * (SEQ / 4); m < (g + 1) * (SEQ / 4); m++)
        acc += sc[m] * Vp[(size_t)m * D_HEAD + t];
    op[g][t] = acc;
    __syncthreads();
    if (g == 0) {
        float r = (op[0][t] + op[1][t] + op[2][t] + op[3][t]) / gsum;
        O[((size_t)b * SEQ + row) * D_MODEL + h * D_HEAD + t] = r;
    }
}

// ---------------------------------------------------------------- add + LN
// grid: NTOK, block: 256 (2 elems/thread). Safe for Out==R (in-place).
__device__ inline float block_sum_256(float v, float* tmp) {
#pragma unroll
    for (int off = 32; off > 0; off >>= 1) v += __shfl_down(v, off, 64);
    if ((threadIdx.x & 63) == 0) tmp[threadIdx.x >> 6] = v;
    __syncthreads();
    return tmp[0] + tmp[1] + tmp[2] + tmp[3];
}

__global__ void add_norm_kernel(const float* __restrict__ A,
                                const float* __restrict__ R,
                                const float* __restrict__ ga,
                                const float* __restrict__ gb,
                                float* __restrict__ Out) {
    int tok = blockIdx.x, tid = threadIdx.x;
    __shared__ float t1[4], t2[4];
    size_t base = (size_t)tok * D_MODEL;
    float z0 = A[base + tid]       + R[base + tid];
    float z1 = A[base + tid + 256] + R[base + tid + 256];
    float s = block_sum_256(z0 + z1, t1);
    float mu = s * (1.f / (float)D_MODEL);
    float d0 = z0 - mu, d1 = z1 - mu;
    float ss = block_sum_256(d0 * d0 + d1 * d1, t2);
    float sigma = sqrtf(ss * (1.f / (float)(D_MODEL - 1)));
    float inv = 1.f / (sigma + LN_EPS);
    Out[base + tid]       = d0 * inv * ga[tid]       + gb[tid];
    Out[base + tid + 256] = d1 * inv * ga[tid + 256] + gb[tid + 256];
}

// ---------------------------------------------------------------- FFN1 (relu)
// grid: NTOK/4, block: 256
__global__ void ffn1_kernel(const float* __restrict__ X,
                            const float* __restrict__ w1,
                            const float* __restrict__ b1,
                            float* __restrict__ H) {
    int tok0 = blockIdx.x * 4, tid = threadIdx.x;
    __shared__ float xs[4][D_MODEL];
    const float* xg = X + (size_t)tok0 * D_MODEL;
    for (int idx = tid; idx < 4 * D_MODEL; idx += 256)
        ((float*)xs)[idx] = xg[idx];
    __syncthreads();

    for (int f = tid; f < D_INNER; f += 256) {
        const float4* wr = (const float4*)(w1 + (size_t)f * D_MODEL);
        float a0 = 0.f, a1 = 0.f, a2 = 0.f, a3 = 0.f;
#pragma unroll 8
        for (int j = 0; j < D_MODEL / 4; j++) {
            float4 w = wr[j];
            a0 += w.x*xs[0][4*j] + w.y*xs[0][4*j+1] + w.z*xs[0][4*j+2] + w.w*xs[0][4*j+3];
            a1 += w.x*xs[1][4*j] + w.y*xs[1][4*j+1] + w.z*xs[1][4*j+2] + w.w*xs[1][4*j+3];
            a2 += w.x*xs[2][4*j] + w.y*xs[2][4*j+1] + w.z*xs[2][4*j+2] + w.w*xs[2][4*j+3];
            a3 += w.x*xs[3][4*j] + w.y*xs[3][4*j+1] + w.z*xs[3][4*j+2] + w.w*xs[3][4*j+3];
        }
        float bb = b1[f];
        H[(size_t)(tok0 + 0) * D_INNER + f] = fmaxf(a0 + bb, 0.f);
        H[(size_t)(tok0 + 1) * D_INNER + f] = fmaxf(a1 + bb, 0.f);
        H[(size_t)(tok0 + 2) * D_INNER + f] = fmaxf(a2 + bb, 0.f);
        H[(size_t)(tok0 + 3) * D_INNER + f] = fmaxf(a3 + bb, 0.f);
    }
}

// ---------------------------------------------------------------- FFN2
// grid: NTOK/4, block: 256
__global__ void ffn2_kernel(const float* __restrict__ H,
                            const float* __restrict__ w2,
                            const float* __restrict__ b2,
                            float* __restrict__ O) {
    int tok0 = blockIdx.x * 4, tid = threadIdx.x;
    __shared__ float hs[4][D_INNER];
    const float* hg = H + (size_t)tok0 * D_INNER;
    for (int idx = tid; idx < 4 * D_INNER; idx += 256)
        ((float*)hs)[idx] = hg[idx];
    __syncthreads();

    for (int d = tid; d < D_MODEL; d += 256) {
        const float4* wr = (const float4*)(w2 + (size_t)d * D_INNER);
        float a0 = 0.f, a1 = 0.f, a2 = 0.f, a3 = 0.f;
#pragma unroll 8
        for (int j = 0; j < D_INNER / 4; j++) {
            float4 w = wr[j];
            a0 += w.x*hs[0][4*j] + w.y*hs[0][4*j+1] + w.z*hs[0][4*j+2] + w.w*hs[0][4*j+3];
            a1 += w.x*hs[1][4*j] + w.y*hs[1][4*j+1] + w.z*hs[1][4*j+2] + w.w*hs[1][4*j+3];
            a2 += w.x*hs[2][4*j] + w.y*hs[2][4*j+1] + w.z*hs[2][4*j+2] + w.w*hs[2][4*j+3];
            a3 += w.x*hs[3][4*j] + w.y*hs[3][4*j+1] + w.z*hs[3][4*j+2] + w.w*hs[3][4*j+3];
        }
        float bb = b2[d];
        O[(size_t)(tok0 + 0) * D_MODEL + d] = a0 + bb;
        O[(size_t)(tok0 + 1) * D_MODEL + d] = a1 + bb;
        O[(size_t)(tok0 + 2) * D_MODEL + d] = a2 + bb;
        O[(size_t)(tok0 + 3) * D_MODEL + d] = a3 + bb;
    }
}

// ---------------------------------------------------------------- launch
extern "C" void kernel_launch(void* const* d_in, const int* in_sizes, int n_in,
                              void* d_out, int out_size, void* d_ws, size_t ws_size,
                              hipStream_t stream) {
    const float* x     = (const float*)d_in[0];
    const float* pe    = (const float*)d_in[1];
    const float* w_qs  = (const float*)d_in[2];
    const float* w_ks  = (const float*)d_in[3];
    const float* w_vs  = (const float*)d_in[4];
    const float* ln1_a = (const float*)d_in[5];
    const float* ln1_b = (const float*)d_in[6];
    const float* w1    = (const float*)d_in[7];
    const float* b1    = (const float*)d_in[8];
    const float* w2    = (const float*)d_in[9];
    const float* b2    = (const float*)d_in[10];
    const float* ln2_a = (const float*)d_in[11];
    const float* ln2_b = (const float*)d_in[12];
    float* out = (float*)d_out;

    float* ws = (float*)d_ws;
    const size_t NXD = (size_t)NTOK * D_MODEL;   // 2M floats
    float* X  = ws;
    float* Qb = X  + NXD;
    float* Kb = Qb + NXD;
    float* Vb = Kb + NXD;
    float* Ob = Vb + NXD;
    float* Hb = Ob + NXD;                        // 4M floats

    add_pos_kernel<<<(NXD + 255) / 256, 256, 0, stream>>>(x, pe, X);

    for (int i = 0; i < N_LAYERS; i++) {
        const float* wq = w_qs + (size_t)i * N_HEAD * D_MODEL * D_HEAD;
        const float* wk = w_ks + (size_t)i * N_HEAD * D_MODEL * D_HEAD;
        const float* wv = w_vs + (size_t)i * N_HEAD * D_MODEL * D_HEAD;

        qkv_proj_kernel<<<dim3(NTOK / 4, N_HEAD, 3), 64, 0, stream>>>(
            X, wq, wk, wv, Qb, Kb, Vb);

        attention_kernel<<<dim3(SEQ, BATCH, N_HEAD), 256, 0, stream>>>(
            Qb, Kb, Vb, Ob);

        add_norm_kernel<<<NTOK, 256, 0, stream>>>(
            Ob, X, ln1_a + i * D_MODEL, ln1_b + i * D_MODEL, X);

        ffn1_kernel<<<NTOK / 4, 256, 0, stream>>>(
            X, w1 + (size_t)i * D_INNER * D_MODEL, b1 + (size_t)i * D_INNER, Hb);

        ffn2_kernel<<<NTOK / 4, 256, 0, stream>>>(
            Hb, w2 + (size_t)i * D_MODEL * D_INNER, b2 + (size_t)i * D_MODEL, Ob);

        float* dst = (i == N_LAYERS - 1) ? out : X;
        add_norm_kernel<<<NTOK, 256, 0, stream>>>(
            Ob, X, ln2_a + i * D_MODEL, ln2_b + i * D_MODEL, dst);
    }
}

// Round 2
// 1905.301 us; speedup vs baseline: 2.4931x; 2.4931x over previous
//
#include <hip/hip_runtime.h>
#include <math.h>

#define D_MODEL 512
#define SEQ     1024
#define BATCH   4
#define N_LAYERS 2
#define N_HEAD  8
#define D_HEAD  64
#define D_INNER 1024
#define NTOK    (BATCH*SEQ)   // 4096
#define LN_EPS  1e-3f
#define TQ      64
#define TK      64

// ---------------------------------------------------------------- add pos enc
__global__ void add_pos_kernel(const float* __restrict__ x,
                               const float* __restrict__ pe,
                               float* __restrict__ X) {
    int idx = blockIdx.x * blockDim.x + threadIdx.x;   // over NTOK*D_MODEL
    int l = (idx / D_MODEL) % SEQ;
    int d = idx % D_MODEL;
    X[idx] = x[idx] + pe[l * D_MODEL + d];
}

// ---------------------------------------------------------------- QKV proj
// grid: (NTOK/4, N_HEAD, 3), block: 64
// Q/K/V layout: [h][b*SEQ + l][dk]
__global__ void qkv_proj_kernel(const float* __restrict__ X,
                                const float* __restrict__ Wq,
                                const float* __restrict__ Wk,
                                const float* __restrict__ Wv,
                                float* __restrict__ Q,
                                float* __restrict__ Kb,
                                float* __restrict__ Vb) {
    int tok0 = blockIdx.x * 4;
    int h    = blockIdx.y;
    int which = blockIdx.z;
    const float* W = (which == 0) ? Wq : (which == 1) ? Wk : Wv;
    float*       O = (which == 0) ? Q  : (which == 1) ? Kb : Vb;

    __shared__ float xs[4][D_MODEL];
    const float* xg = X + (size_t)tok0 * D_MODEL;
    for (int idx = threadIdx.x; idx < 4 * D_MODEL; idx += 64)
        ((float*)xs)[idx] = xg[idx];
    __syncthreads();

    const float* Wh = W + (size_t)h * D_MODEL * D_HEAD;
    int t = threadIdx.x;
    float a0 = 0.f, a1 = 0.f, a2 = 0.f, a3 = 0.f;
    for (int d = 0; d < D_MODEL; d++) {
        float w = Wh[d * D_HEAD + t];
        a0 += xs[0][d] * w;
        a1 += xs[1][d] * w;
        a2 += xs[2][d] * w;
        a3 += xs[3][d] * w;
    }
    float* Oh = O + ((size_t)h * NTOK + tok0) * D_HEAD + t;
    Oh[0 * D_HEAD] = a0;
    Oh[1 * D_HEAD] = a1;
    Oh[2 * D_HEAD] = a2;
    Oh[3 * D_HEAD] = a3;
}

// ---------------------------------------------------------------- attention
// Flash-style: grid (SEQ/TQ, BATCH, N_HEAD), block 256.
// Thread tid -> (row r = tid>>2 within Q-tile, dim-quarter dq = tid&3).
// K/V staged in LDS per 64-key tile, shared by the whole block.
// Online softmax state (m, l) kept redundantly in the 4 threads of a row.
__global__ __launch_bounds__(256, 2)
void attention_kernel(const float* __restrict__ Q,
                      const float* __restrict__ K,
                      const float* __restrict__ V,
                      float* __restrict__ O) {
    const int qt = blockIdx.x, b = blockIdx.y, h = blockIdx.z;
    const int tid = threadIdx.x;
    const int r  = tid >> 2;   // 0..63: row within Q tile
    const int dq = tid & 3;    // dim quarter: dims [dq*16, dq*16+16)
    const int hb = h * BATCH + b;
    const size_t base = (size_t)hb * SEQ * D_HEAD;

    __shared__ float kt[TK * D_HEAD];   // 16 KB
    __shared__ float vt[TK * D_HEAD];   // 16 KB

    // Q fragment for this (row, quarter) in registers
    float4 q[4];
    {
        const float4* qp = (const float4*)(Q + base + (size_t)(qt * TQ + r) * D_HEAD + dq * 16);
        q[0] = qp[0]; q[1] = qp[1]; q[2] = qp[2]; q[3] = qp[3];
    }

    float acc[16];
#pragma unroll
    for (int i = 0; i < 16; i++) acc[i] = 0.f;
    float mrun = -1e30f, lrun = 0.f;
    const float inv_temper = 0.04419417382415922f;  // 1/sqrt(512)

    for (int t0 = 0; t0 < SEQ; t0 += TK) {
        // cooperative tile load: 64 keys x 64 dims, K and V
        {
            const float4* kg = (const float4*)(K + base + (size_t)t0 * D_HEAD);
            const float4* vg = (const float4*)(V + base + (size_t)t0 * D_HEAD);
            float4* ks = (float4*)kt;
            float4* vs = (float4*)vt;
#pragma unroll
            for (int i = 0; i < TK * D_HEAD / 4 / 256; i++) {
                ks[tid + i * 256] = kg[tid + i * 256];
                vs[tid + i * 256] = vg[tid + i * 256];
            }
        }
        __syncthreads();

        // process tile in chunks of 16 keys (keeps sc[] in registers w/o huge unroll)
        for (int jc = 0; jc < TK / 16; jc++) {
            const float* kbase = kt + jc * 16 * D_HEAD + dq * 16;
            float sc[16];
            float tmax = -1e30f;
#pragma unroll
            for (int j = 0; j < 16; j++) {
                const float4* kr = (const float4*)(kbase + j * D_HEAD);
                float s = 0.f;
#pragma unroll
                for (int kk = 0; kk < 4; kk++) {
                    float4 kv = kr[kk];
                    s += q[kk].x * kv.x + q[kk].y * kv.y
                       + q[kk].z * kv.z + q[kk].w * kv.w;
                }
                // reduce partial dot across the 4 threads of this row
                s += __shfl_xor(s, 1, 64);
                s += __shfl_xor(s, 2, 64);
                s *= inv_temper;
                sc[j] = s;
                tmax = fmaxf(tmax, s);
            }
            float mn    = fmaxf(mrun, tmax);
            float alpha = __expf(mrun - mn);
            lrun *= alpha;
#pragma unroll
            for (int i = 0; i < 16; i++) acc[i] *= alpha;

            const float* vbase = vt + jc * 16 * D_HEAD + dq * 16;
#pragma unroll
            for (int j = 0; j < 16; j++) {
                float p = __expf(sc[j] - mn);
                lrun += p;
                const float4* vr = (const float4*)(vbase + j * D_HEAD);
#pragma unroll
                for (int kk = 0; kk < 4; kk++) {
                    float4 vv = vr[kk];
                    acc[4 * kk + 0] += p * vv.x;
                    acc[4 * kk + 1] += p * vv.y;
                    acc[4 * kk + 2] += p * vv.z;
                    acc[4 * kk + 3] += p * vv.w;
                }
            }
            mrun = mn;
        }
        __syncthreads();
    }

    float inv = 1.f / lrun;
    // head-concat layout: O[b][row][h*64 + dq*16 + d]
    float4* op = (float4*)(O + ((size_t)b * SEQ + qt * TQ + r) * D_MODEL + h * D_HEAD + dq * 16);
#pragma unroll
    for (int kk = 0; kk < 4; kk++)
        op[kk] = make_float4(acc[4 * kk + 0] * inv, acc[4 * kk + 1] * inv,
                             acc[4 * kk + 2] * inv, acc[4 * kk + 3] * inv);
}

// ---------------------------------------------------------------- add + LN
// grid: NTOK, block: 256 (2 elems/thread). Safe for Out==R (in-place).
__device__ inline float block_sum_256(float v, float* tmp) {
#pragma unroll
    for (int off = 32; off > 0; off >>= 1) v += __shfl_down(v, off, 64);
    if ((threadIdx.x & 63) == 0) tmp[threadIdx.x >> 6] = v;
    __syncthreads();
    return tmp[0] + tmp[1] + tmp[2] + tmp[3];
}

__global__ void add_norm_kernel(const float* __restrict__ A,
                                const float* __restrict__ R,
                                const float* __restrict__ ga,
                                const float* __restrict__ gb,
                                float* __restrict__ Out) {
    int tok = blockIdx.x, tid = threadIdx.x;
    __shared__ float t1[4], t2[4];
    size_t base = (size_t)tok * D_MODEL;
    float z0 = A[base + tid]       + R[base + tid];
    float z1 = A[base + tid + 256] + R[base + tid + 256];
    float s = block_sum_256(z0 + z1, t1);
    float mu = s * (1.f / (float)D_MODEL);
    float d0 = z0 - mu, d1 = z1 - mu;
    float ss = block_sum_256(d0 * d0 + d1 * d1, t2);
    float sigma = sqrtf(ss * (1.f / (float)(D_MODEL - 1)));
    float inv = 1.f / (sigma + LN_EPS);
    Out[base + tid]       = d0 * inv * ga[tid]       + gb[tid];
    Out[base + tid + 256] = d1 * inv * ga[tid + 256] + gb[tid + 256];
}

// ---------------------------------------------------------------- FFN1 (relu)
// grid: NTOK/4, block: 256
__global__ void ffn1_kernel(const float* __restrict__ X,
                            const float* __restrict__ w1,
                            const float* __restrict__ b1,
                            float* __restrict__ H) {
    int tok0 = blockIdx.x * 4, tid = threadIdx.x;
    __shared__ float xs[4][D_MODEL];
    const float* xg = X + (size_t)tok0 * D_MODEL;
    for (int idx = tid; idx < 4 * D_MODEL; idx += 256)
        ((float*)xs)[idx] = xg[idx];
    __syncthreads();

    for (int f = tid; f < D_INNER; f += 256) {
        const float4* wr = (const float4*)(w1 + (size_t)f * D_MODEL);
        float a0 = 0.f, a1 = 0.f, a2 = 0.f, a3 = 0.f;
#pragma unroll 8
        for (int j = 0; j < D_MODEL / 4; j++) {
            float4 w = wr[j];
            a0 += w.x*xs[0][4*j] + w.y*xs[0][4*j+1] + w.z*xs[0][4*j+2] + w.w*xs[0][4*j+3];
            a1 += w.x*xs[1][4*j] + w.y*xs[1][4*j+1] + w.z*xs[1][4*j+2] + w.w*xs[1][4*j+3];
            a2 += w.x*xs[2][4*j] + w.y*xs[2][4*j+1] + w.z*xs[2][4*j+2] + w.w*xs[2][4*j+3];
            a3 += w.x*xs[3][4*j] + w.y*xs[3][4*j+1] + w.z*xs[3][4*j+2] + w.w*xs[3][4*j+3];
        }
        float bb = b1[f];
        H[(size_t)(tok0 + 0) * D_INNER + f] = fmaxf(a0 + bb, 0.f);
        H[(size_t)(tok0 + 1) * D_INNER + f] = fmaxf(a1 + bb, 0.f);
        H[(size_t)(tok0 + 2) * D_INNER + f] = fmaxf(a2 + bb, 0.f);
        H[(size_t)(tok0 + 3) * D_INNER + f] = fmaxf(a3 + bb, 0.f);
    }
}

// ---------------------------------------------------------------- FFN2
// grid: NTOK/4, block: 256
__global__ void ffn2_kernel(const float* __restrict__ H,
                            const float* __restrict__ w2,
                            const float* __restrict__ b2,
                            float* __restrict__ O) {
    int tok0 = blockIdx.x * 4, tid = threadIdx.x;
    __shared__ float hs[4][D_INNER];
    const float* hg = H + (size_t)tok0 * D_INNER;
    for (int idx = tid; idx < 4 * D_INNER; idx += 256)
        ((float*)hs)[idx] = hg[idx];
    __syncthreads();

    for (int d = tid; d < D_MODEL; d += 256) {
        const float4* wr = (const float4*)(w2 + (size_t)d * D_INNER);
        float a0 = 0.f, a1 = 0.f, a2 = 0.f, a3 = 0.f;
#pragma unroll 8
        for (int j = 0; j < D_INNER / 4; j++) {
            float4 w = wr[j];
            a0 += w.x*hs[0][4*j] + w.y*hs[0][4*j+1] + w.z*hs[0][4*j+2] + w.w*hs[0][4*j+3];
            a1 += w.x*hs[1][4*j] + w.y*hs[1][4*j+1] + w.z*hs[1][4*j+2] + w.w*hs[1][4*j+3];
            a2 += w.x*hs[2][4*j] + w.y*hs[2][4*j+1] + w.z*hs[2][4*j+2] + w.w*hs[2][4*j+3];
            a3 += w.x*hs[3][4*j] + w.y*hs[3][4*j+1] + w.z*hs[3][4*j+2] + w.w*hs[3][4*j+3];
        }
        float bb = b2[d];
        O[(size_t)(tok0 + 0) * D_MODEL + d] = a0 + bb;
        O[(size_t)(tok0 + 1) * D_MODEL + d] = a1 + bb;
        O[(size_t)(tok0 + 2) * D_MODEL + d] = a2 + bb;
        O[(size_t)(tok0 + 3) * D_MODEL + d] = a3 + bb;
    }
}

// ---------------------------------------------------------------- launch
extern "C" void kernel_launch(void* const* d_in, const int* in_sizes, int n_in,
                              void* d_out, int out_size, void* d_ws, size_t ws_size,
                              hipStream_t stream) {
    const float* x     = (const float*)d_in[0];
    const float* pe    = (const float*)d_in[1];
    const float* w_qs  = (const float*)d_in[2];
    const float* w_ks  = (const float*)d_in[3];
    const float* w_vs  = (const float*)d_in[4];
    const float* ln1_a = (const float*)d_in[5];
    const float* ln1_b = (const float*)d_in[6];
    const float* w1    = (const float*)d_in[7];
    const float* b1    = (const float*)d_in[8];
    const float* w2    = (const float*)d_in[9];
    const float* b2    = (const float*)d_in[10];
    const float* ln2_a = (const float*)d_in[11];
    const float* ln2_b = (const float*)d_in[12];
    float* out = (float*)d_out;

    float* ws = (float*)d_ws;
    const size_t NXD = (size_t)NTOK * D_MODEL;   // 2M floats
    float* X  = ws;
    float* Qb = X  + NXD;
    float* Kb = Qb + NXD;
    float* Vb = Kb + NXD;
    float* Ob = Vb + NXD;
    float* Hb = Ob + NXD;                        // 4M floats

    add_pos_kernel<<<(NXD + 255) / 256, 256, 0, stream>>>(x, pe, X);

    for (int i = 0; i < N_LAYERS; i++) {
        const float* wq = w_qs + (size_t)i * N_HEAD * D_MODEL * D_HEAD;
        const float* wk = w_ks + (size_t)i * N_HEAD * D_MODEL * D_HEAD;
        const float* wv = w_vs + (size_t)i * N_HEAD * D_MODEL * D_HEAD;

        qkv_proj_kernel<<<dim3(NTOK / 4, N_HEAD, 3), 64, 0, stream>>>(
            X, wq, wk, wv, Qb, Kb, Vb);

        attention_kernel<<<dim3(SEQ / TQ, BATCH, N_HEAD), 256, 0, stream>>>(
            Qb, Kb, Vb, Ob);

        add_norm_kernel<<<NTOK, 256, 0, stream>>>(
            Ob, X, ln1_a + i * D_MODEL, ln1_b + i * D_MODEL, X);

        ffn1_kernel<<<NTOK / 4, 256, 0, stream>>>(
            X, w1 + (size_t)i * D_INNER * D_MODEL, b1 + (size_t)i * D_INNER, Hb);

        ffn2_kernel<<<NTOK / 4, 256, 0, stream>>>(
            Hb, w2 + (size_t)i * D_MODEL * D_INNER, b2 + (size_t)i * D_MODEL, Ob);

        float* dst = (i == N_LAYERS - 1) ? out : X;
        add_norm_kernel<<<NTOK, 256, 0, stream>>>(
            Ob, X, ln2_a + i * D_MODEL, ln2_b + i * D_MODEL, dst);
    }
}

// Round 5
// 740.814 us; speedup vs baseline: 6.4119x; 2.5719x over previous
//
#include <hip/hip_runtime.h>
#include <math.h>

#define D_MODEL 512
#define SEQ     1024
#define BATCH   4
#define N_LAYERS 2
#define N_HEAD  8
#define D_HEAD  64
#define D_INNER 1024
#define NTOK    (BATCH*SEQ)   // 4096
#define LN_EPS  1e-3f
#define TQ      64
#define TK      64

typedef float f32x4 __attribute__((ext_vector_type(4)));
typedef short bf16x8 __attribute__((ext_vector_type(8)));
typedef unsigned short ushort_t;
typedef unsigned int uint_t;

// fp32 -> bf16 round-to-nearest-even
__device__ inline ushort_t f2bf(float f) {
    uint_t u = __float_as_uint(f);
    u += 0x7FFFu + ((u >> 16) & 1u);
    return (ushort_t)(u >> 16);
}
__device__ inline float bf2f(ushort_t h) {
    return __uint_as_float((uint_t)h << 16);
}

// ---------------------------------------------------------------- add pos enc
__global__ void add_pos_kernel(const float* __restrict__ x,
                               const float* __restrict__ pe,
                               float* __restrict__ X) {
    int idx = blockIdx.x * blockDim.x + threadIdx.x;   // over NTOK*D_MODEL
    int l = (idx / D_MODEL) % SEQ;
    int d = idx % D_MODEL;
    X[idx] = x[idx] + pe[l * D_MODEL + d];
}

// ---------------------------------------------------------------- weight conv
__global__ void conv_bf16_kernel(const float* __restrict__ src,
                                 ushort_t* __restrict__ dst, int n) {
    int idx = blockIdx.x * 256 + threadIdx.x;
    if (idx < n) dst[idx] = f2bf(src[idx]);
}

// Pack per-layer QKV weights into Bt layout [1536][512] (hi, optional lo):
// row n: which=n>>9, h=(n>>6)&7, d=n&63 ; Bt[n][k] = W_which[h][k][d]
__global__ void conv_qkvw_kernel(const float* __restrict__ wq,
                                 const float* __restrict__ wk,
                                 const float* __restrict__ wv,
                                 ushort_t* __restrict__ hi,
                                 ushort_t* __restrict__ lo) {
    int idx = blockIdx.x * 256 + threadIdx.x;   // over 1536*512
    int n = idx >> 9, k = idx & 511;
    int which = n >> 9, h = (n >> 6) & 7, d = n & 63;
    const float* W = (which == 0) ? wq : (which == 1) ? wk : wv;
    float v = W[((size_t)h * D_MODEL + k) * D_HEAD + d];
    ushort_t hv = f2bf(v);
    hi[idx] = hv;
    if (lo) lo[idx] = f2bf(v - bf2f(hv));
}

// ---------------------------------------------------------------- MFMA GEMM
// C[M,N] = A[M,K] @ Bt[N,K]^T ; A,Bt bf16 row-major, acc fp32.
// Block: 256 thr = 4 waves, tile 64x64, wave tile 32x32 (2x2 of 16x16x32).
// MODE 0: scatter fp32 to Q|K|V buffers in [h][tok][64] layout (N=1536)
// MODE 1: +bias, relu, bf16 out [M,N]
// MODE 2: +bias, fp32 out [M,N]
template<int MODE>
__global__ __launch_bounds__(256, 2)
void gemm_kernel(const ushort_t* __restrict__ A, const ushort_t* __restrict__ Bt,
                 const float* __restrict__ bias, float* __restrict__ outF,
                 ushort_t* __restrict__ outB, int M, int N, int K) {
    __shared__ ushort_t As[64][72];   // +8 pad: keeps 16B align, breaks bank alias
    __shared__ ushort_t Bs[64][72];
    const int tid = threadIdx.x;
    const int m0 = blockIdx.y * 64, n0 = blockIdx.x * 64;
    const int w = tid >> 6, lane = tid & 63;
    const int wm = (w >> 1) * 32, wn = (w & 1) * 32;
    const int col = lane & 15, quad = lane >> 4;

    f32x4 acc[2][2] = {};

    for (int k0 = 0; k0 < K; k0 += 64) {
        __syncthreads();
#pragma unroll
        for (int p = 0; p < 2; p++) {
            int idx = p * 256 + tid;          // 512 tasks: 64 rows x 8 chunks
            int row = idx >> 3, ch = (idx & 7) * 8;
            *(uint4*)(&As[row][ch]) =
                *(const uint4*)(A + (size_t)(m0 + row) * K + k0 + ch);
            *(uint4*)(&Bs[row][ch]) =
                *(const uint4*)(Bt + (size_t)(n0 + row) * K + k0 + ch);
        }
        __syncthreads();
#pragma unroll
        for (int ks = 0; ks < 64; ks += 32) {
            bf16x8 af[2], bf[2];
#pragma unroll
            for (int t = 0; t < 2; t++) {
                af[t] = *(const bf16x8*)(&As[wm + t * 16 + col][ks + quad * 8]);
                bf[t] = *(const bf16x8*)(&Bs[wn + t * 16 + col][ks + quad * 8]);
            }
#pragma unroll
            for (int mt = 0; mt < 2; mt++)
#pragma unroll
                for (int nt = 0; nt < 2; nt++)
                    acc[mt][nt] = __builtin_amdgcn_mfma_f32_16x16x32_bf16(
                        af[mt], bf[nt], acc[mt][nt], 0, 0, 0);
        }
    }

#pragma unroll
    for (int mt = 0; mt < 2; mt++) {
#pragma unroll
        for (int nt = 0; nt < 2; nt++) {
            int n = n0 + wn + nt * 16 + col;
#pragma unroll
            for (int r = 0; r < 4; r++) {
                int m = m0 + wm + mt * 16 + quad * 4 + r;
                float v = acc[mt][nt][r];
                if (MODE == 0) {
                    int which = n >> 9, hd = n & 511;
                    outF[(size_t)which * (size_t)NTOK * D_MODEL
                         + (size_t)(((hd >> 6) * NTOK + m) << 6) + (hd & 63)] = v;
                } else if (MODE == 1) {
                    float t = fmaxf(v + bias[n], 0.f);
                    outB[(size_t)m * N + n] = f2bf(t);
                } else {
                    outF[(size_t)m * N + n] = v + bias[n];
                }
            }
        }
    }
}

// ---------------------------------------------------------------- hi/lo GEMM
// High-precision bf16 GEMM for layer-1 QKV: A fp32 split in-kernel into
// hi+lo bf16; Bt pre-split (hi,lo). acc = Ah*Bh + Ah*Bl + Al*Bh  (~1e-5 rel).
// Epilogue = MODE 0 scatter (fp32 Q|K|V).
__global__ __launch_bounds__(256, 2)
void gemm_hilo_kernel(const float* __restrict__ A,
                      const ushort_t* __restrict__ Bh,
                      const ushort_t* __restrict__ Bl,
                      float* __restrict__ outF, int M, int N, int K) {
    __shared__ ushort_t Ash[64][72];
    __shared__ ushort_t Asl[64][72];
    __shared__ ushort_t Bsh[64][72];
    __shared__ ushort_t Bsl[64][72];
    const int tid = threadIdx.x;
    const int m0 = blockIdx.y * 64, n0 = blockIdx.x * 64;
    const int w = tid >> 6, lane = tid & 63;
    const int wm = (w >> 1) * 32, wn = (w & 1) * 32;
    const int col = lane & 15, quad = lane >> 4;

    f32x4 acc[2][2] = {};

    for (int k0 = 0; k0 < K; k0 += 64) {
        __syncthreads();
        // A: fp32 -> hi/lo bf16. 64 rows x 16 float4 chunks = 1024 tasks.
#pragma unroll
        for (int p = 0; p < 4; p++) {
            int idx = p * 256 + tid;
            int row = idx >> 4, c4 = (idx & 15) * 4;
            float4 v = *(const float4*)(A + (size_t)(m0 + row) * K + k0 + c4);
            ushort_t h0 = f2bf(v.x), h1 = f2bf(v.y), h2 = f2bf(v.z), h3 = f2bf(v.w);
            *(ushort4*)(&Ash[row][c4]) = make_ushort4(h0, h1, h2, h3);
            *(ushort4*)(&Asl[row][c4]) = make_ushort4(
                f2bf(v.x - bf2f(h0)), f2bf(v.y - bf2f(h1)),
                f2bf(v.z - bf2f(h2)), f2bf(v.w - bf2f(h3)));
        }
        // B: hi and lo, 512 tasks each
#pragma unroll
        for (int p = 0; p < 2; p++) {
            int idx = p * 256 + tid;
            int row = idx >> 3, ch = (idx & 7) * 8;
            *(uint4*)(&Bsh[row][ch]) =
                *(const uint4*)(Bh + (size_t)(n0 + row) * K + k0 + ch);
            *(uint4*)(&Bsl[row][ch]) =
                *(const uint4*)(Bl + (size_t)(n0 + row) * K + k0 + ch);
        }
        __syncthreads();
#pragma unroll
        for (int ks = 0; ks < 64; ks += 32) {
            bf16x8 ah[2], al[2], bh[2], bl[2];
#pragma unroll
            for (int t = 0; t < 2; t++) {
                ah[t] = *(const bf16x8*)(&Ash[wm + t * 16 + col][ks + quad * 8]);
                al[t] = *(const bf16x8*)(&Asl[wm + t * 16 + col][ks + quad * 8]);
                bh[t] = *(const bf16x8*)(&Bsh[wn + t * 16 + col][ks + quad * 8]);
                bl[t] = *(const bf16x8*)(&Bsl[wn + t * 16 + col][ks + quad * 8]);
            }
#pragma unroll
            for (int mt = 0; mt < 2; mt++)
#pragma unroll
                for (int nt = 0; nt < 2; nt++) {
                    acc[mt][nt] = __builtin_amdgcn_mfma_f32_16x16x32_bf16(
                        ah[mt], bh[nt], acc[mt][nt], 0, 0, 0);
                    acc[mt][nt] = __builtin_amdgcn_mfma_f32_16x16x32_bf16(
                        ah[mt], bl[nt], acc[mt][nt], 0, 0, 0);
                    acc[mt][nt] = __builtin_amdgcn_mfma_f32_16x16x32_bf16(
                        al[mt], bh[nt], acc[mt][nt], 0, 0, 0);
                }
        }
    }

#pragma unroll
    for (int mt = 0; mt < 2; mt++) {
#pragma unroll
        for (int nt = 0; nt < 2; nt++) {
            int n = n0 + wn + nt * 16 + col;
            int which = n >> 9, hd = n & 511;
#pragma unroll
            for (int r = 0; r < 4; r++) {
                int m = m0 + wm + mt * 16 + quad * 4 + r;
                outF[(size_t)which * (size_t)NTOK * D_MODEL
                     + (size_t)(((hd >> 6) * NTOK + m) << 6) + (hd & 63)]
                    = acc[mt][nt][r];
            }
        }
    }
}

// ---------------------------------------------------------------- attention
// Flash-style, fp32 Q/K/V. grid (SEQ/TQ, BATCH, N_HEAD), block 256.
// Thread = (row r=tid>>2, dim-quarter dq=tid&3); online softmax in registers.
__global__ __launch_bounds__(256, 2)
void attention_kernel(const float* __restrict__ Q,
                      const float* __restrict__ K,
                      const float* __restrict__ V,
                      float* __restrict__ O) {
    const int qt = blockIdx.x, b = blockIdx.y, h = blockIdx.z;
    const int tid = threadIdx.x;
    const int r  = tid >> 2;
    const int dq = tid & 3;
    const int hb = h * BATCH + b;
    const size_t base = (size_t)hb * SEQ * D_HEAD;

    __shared__ float kt[TK * D_HEAD];   // 16 KB
    __shared__ float vt[TK * D_HEAD];   // 16 KB

    float4 q[4];
    {
        const float4* qp = (const float4*)(Q + base + (size_t)(qt * TQ + r) * D_HEAD + dq * 16);
        q[0] = qp[0]; q[1] = qp[1]; q[2] = qp[2]; q[3] = qp[3];
    }

    float acc[16];
#pragma unroll
    for (int i = 0; i < 16; i++) acc[i] = 0.f;
    float mrun = -1e30f, lrun = 0.f;
    const float inv_temper = 0.04419417382415922f;  // 1/sqrt(512)

    for (int t0 = 0; t0 < SEQ; t0 += TK) {
        {
            const float4* kg = (const float4*)(K + base + (size_t)t0 * D_HEAD);
            const float4* vg = (const float4*)(V + base + (size_t)t0 * D_HEAD);
            float4* ks = (float4*)kt;
            float4* vs = (float4*)vt;
#pragma unroll
            for (int i = 0; i < TK * D_HEAD / 4 / 256; i++) {
                ks[tid + i * 256] = kg[tid + i * 256];
                vs[tid + i * 256] = vg[tid + i * 256];
            }
        }
        __syncthreads();

        for (int jc = 0; jc < TK / 16; jc++) {
            const float* kbase = kt + jc * 16 * D_HEAD + dq * 16;
            float sc[16];
            float tmax = -1e30f;
#pragma unroll
            for (int j = 0; j < 16; j++) {
                const float4* kr = (const float4*)(kbase + j * D_HEAD);
                float s = 0.f;
#pragma unroll
                for (int kk = 0; kk < 4; kk++) {
                    float4 kv = kr[kk];
                    s += q[kk].x * kv.x + q[kk].y * kv.y
                       + q[kk].z * kv.z + q[kk].w * kv.w;
                }
                s += __shfl_xor(s, 1, 64);
                s += __shfl_xor(s, 2, 64);
                s *= inv_temper;
                sc[j] = s;
                tmax = fmaxf(tmax, s);
            }
            float mn    = fmaxf(mrun, tmax);
            float alpha = __expf(mrun - mn);
            lrun *= alpha;
#pragma unroll
            for (int i = 0; i < 16; i++) acc[i] *= alpha;

            const float* vbase = vt + jc * 16 * D_HEAD + dq * 16;
#pragma unroll
            for (int j = 0; j < 16; j++) {
                float p = __expf(sc[j] - mn);
                lrun += p;
                const float4* vr = (const float4*)(vbase + j * D_HEAD);
#pragma unroll
                for (int kk = 0; kk < 4; kk++) {
                    float4 vv = vr[kk];
                    acc[4 * kk + 0] += p * vv.x;
                    acc[4 * kk + 1] += p * vv.y;
                    acc[4 * kk + 2] += p * vv.z;
                    acc[4 * kk + 3] += p * vv.w;
                }
            }
            mrun = mn;
        }
        __syncthreads();
    }

    float inv = 1.f / lrun;
    float4* op = (float4*)(O + ((size_t)b * SEQ + qt * TQ + r) * D_MODEL + h * D_HEAD + dq * 16);
#pragma unroll
    for (int kk = 0; kk < 4; kk++)
        op[kk] = make_float4(acc[4 * kk + 0] * inv, acc[4 * kk + 1] * inv,
                             acc[4 * kk + 2] * inv, acc[4 * kk + 3] * inv);
}

// ---------------------------------------------------------------- add + LN
__device__ inline float block_sum_256(float v, float* tmp) {
#pragma unroll
    for (int off = 32; off > 0; off >>= 1) v += __shfl_down(v, off, 64);
    if ((threadIdx.x & 63) == 0) tmp[threadIdx.x >> 6] = v;
    __syncthreads();
    return tmp[0] + tmp[1] + tmp[2] + tmp[3];
}

// Writes fp32 Out AND bf16 OutBf. Safe for Out==R (in-place).
__global__ void add_norm_kernel(const float* __restrict__ A,
                                const float* __restrict__ R,
                                const float* __restrict__ ga,
                                const float* __restrict__ gb,
                                float* __restrict__ Out,
                                ushort_t* __restrict__ OutBf) {
    int tok = blockIdx.x, tid = threadIdx.x;
    __shared__ float t1[4], t2[4];
    size_t base = (size_t)tok * D_MODEL;
    float z0 = A[base + tid]       + R[base + tid];
    float z1 = A[base + tid + 256] + R[base + tid + 256];
    float s = block_sum_256(z0 + z1, t1);
    float mu = s * (1.f / (float)D_MODEL);
    float d0 = z0 - mu, d1 = z1 - mu;
    float ss = block_sum_256(d0 * d0 + d1 * d1, t2);
    float sigma = sqrtf(ss * (1.f / (float)(D_MODEL - 1)));
    float inv = 1.f / (sigma + LN_EPS);
    float r0 = d0 * inv * ga[tid]       + gb[tid];
    float r1 = d1 * inv * ga[tid + 256] + gb[tid + 256];
    Out[base + tid]         = r0;
    Out[base + tid + 256]   = r1;
    OutBf[base + tid]       = f2bf(r0);
    OutBf[base + tid + 256] = f2bf(r1);
}

// ---------------------------------------------------------------- launch
extern "C" void kernel_launch(void* const* d_in, const int* in_sizes, int n_in,
                              void* d_out, int out_size, void* d_ws, size_t ws_size,
                              hipStream_t stream) {
    const float* x     = (const float*)d_in[0];
    const float* pe    = (const float*)d_in[1];
    const float* w_qs  = (const float*)d_in[2];
    const float* w_ks  = (const float*)d_in[3];
    const float* w_vs  = (const float*)d_in[4];
    const float* ln1_a = (const float*)d_in[5];
    const float* ln1_b = (const float*)d_in[6];
    const float* w1    = (const float*)d_in[7];
    const float* b1    = (const float*)d_in[8];
    const float* w2    = (const float*)d_in[9];
    const float* b2    = (const float*)d_in[10];
    const float* ln2_a = (const float*)d_in[11];
    const float* ln2_b = (const float*)d_in[12];
    float* out = (float*)d_out;

    const size_t NXD = (size_t)NTOK * D_MODEL;       // 2M elements
    char* p = (char*)d_ws;
    float*    X    = (float*)p;     p += NXD * 4;                 // 8 MB
    float*    Ob   = (float*)p;     p += NXD * 4;                 // 8 MB
    ushort_t* Xbf  = (ushort_t*)p;  p += NXD * 2;                 // 4 MB
    float*    QKVf = (float*)p;     p += 3 * NXD * 4;             // 24 MB (Q|K|V fp32)
    ushort_t* Wqkv = (ushort_t*)p;  p += (size_t)N_LAYERS * 1536 * 512 * 2;  // 3 MB (hi)
    ushort_t* WqkvL= (ushort_t*)p;  p += (size_t)1536 * 512 * 2;  // 1.5 MB (lo, layer 0)
    ushort_t* W1b  = (ushort_t*)p;  p += (size_t)N_LAYERS * D_INNER * D_MODEL * 2;  // 2 MB
    ushort_t* W2b  = (ushort_t*)p;  /* 2 MB */
    // H (bf16, 8 MB) aliases QKVf: dead ranges don't overlap in time.
    ushort_t* Hbf  = (ushort_t*)QKVf;

    add_pos_kernel<<<(int)(NXD / 256), 256, 0, stream>>>(x, pe, X);

    for (int i = 0; i < N_LAYERS; i++) {
        conv_qkvw_kernel<<<1536 * 512 / 256, 256, 0, stream>>>(
            w_qs + (size_t)i * N_HEAD * D_MODEL * D_HEAD,
            w_ks + (size_t)i * N_HEAD * D_MODEL * D_HEAD,
            w_vs + (size_t)i * N_HEAD * D_MODEL * D_HEAD,
            Wqkv + (size_t)i * 1536 * 512,
            (i == 0) ? WqkvL : (ushort_t*)nullptr);
    }
    conv_bf16_kernel<<<(N_LAYERS * D_INNER * D_MODEL) / 256, 256, 0, stream>>>(
        w1, W1b, N_LAYERS * D_INNER * D_MODEL);
    conv_bf16_kernel<<<(N_LAYERS * D_MODEL * D_INNER) / 256, 256, 0, stream>>>(
        w2, W2b, N_LAYERS * D_MODEL * D_INNER);

    float* Qb = QKVf;
    float* Kb = QKVf + NXD;
    float* Vb = QKVf + 2 * NXD;

    for (int i = 0; i < N_LAYERS; i++) {
        // QKV: M=4096, N=1536, K=512
        if (i == 0) {
            // layer 1: inputs have huge pos-enc values -> hi/lo split GEMM
            gemm_hilo_kernel<<<dim3(1536 / 64, NTOK / 64), 256, 0, stream>>>(
                X, Wqkv, WqkvL, QKVf, NTOK, 1536, D_MODEL);
        } else {
            gemm_kernel<0><<<dim3(1536 / 64, NTOK / 64), 256, 0, stream>>>(
                Xbf, Wqkv + (size_t)i * 1536 * 512, nullptr, QKVf, nullptr,
                NTOK, 1536, D_MODEL);
        }

        attention_kernel<<<dim3(SEQ / TQ, BATCH, N_HEAD), 256, 0, stream>>>(
            Qb, Kb, Vb, Ob);

        add_norm_kernel<<<NTOK, 256, 0, stream>>>(
            Ob, X, ln1_a + i * D_MODEL, ln1_b + i * D_MODEL, X, Xbf);

        // FFN1: M=4096, N=1024, K=512, bias+relu -> bf16 H (aliases QKVf)
        gemm_kernel<1><<<dim3(D_INNER / 64, NTOK / 64), 256, 0, stream>>>(
            Xbf, W1b + (size_t)i * D_INNER * D_MODEL, b1 + (size_t)i * D_INNER,
            nullptr, Hbf, NTOK, D_INNER, D_MODEL);

        // FFN2: M=4096, N=512, K=1024, bias -> fp32 Ob
        gemm_kernel<2><<<dim3(D_MODEL / 64, NTOK / 64), 256, 0, stream>>>(
            Hbf, W2b + (size_t)i * D_MODEL * D_INNER, b2 + (size_t)i * D_MODEL,
            Ob, nullptr, NTOK, D_MODEL, D_INNER);

        float* dst = (i == N_LAYERS - 1) ? out : X;
        add_norm_kernel<<<NTOK, 256, 0, stream>>>(
            Ob, X, ln2_a + i * D_MODEL, ln2_b + i * D_MODEL, dst, Xbf);
    }
}

// Round 6
// 425.363 us; speedup vs baseline: 11.1670x; 1.7416x over previous
//
#include <hip/hip_runtime.h>
#include <math.h>

#define D_MODEL 512
#define SEQ     1024
#define BATCH   4
#define N_LAYERS 2
#define N_HEAD  8
#define D_HEAD  64
#define D_INNER 1024
#define NTOK    (BATCH*SEQ)   // 4096
#define LN_EPS  1e-3f

typedef float f32x4 __attribute__((ext_vector_type(4)));
typedef short bf16x8 __attribute__((ext_vector_type(8)));
typedef unsigned short ushort_t;
typedef unsigned int uint_t;

// fp32 -> bf16 round-to-nearest-even
__device__ inline ushort_t f2bf(float f) {
    uint_t u = __float_as_uint(f);
    u += 0x7FFFu + ((u >> 16) & 1u);
    return (ushort_t)(u >> 16);
}
__device__ inline float bf2f(ushort_t h) {
    return __uint_as_float((uint_t)h << 16);
}

// ---------------------------------------------------------------- add pos enc
__global__ void add_pos_kernel(const float* __restrict__ x,
                               const float* __restrict__ pe,
                               float* __restrict__ X) {
    int idx = blockIdx.x * blockDim.x + threadIdx.x;   // over NTOK*D_MODEL
    int l = (idx / D_MODEL) % SEQ;
    int d = idx % D_MODEL;
    X[idx] = x[idx] + pe[l * D_MODEL + d];
}

// ---------------------------------------------------------------- weight conv
__global__ void conv_bf16_kernel(const float* __restrict__ src,
                                 ushort_t* __restrict__ dst, int n) {
    int idx = blockIdx.x * 256 + threadIdx.x;
    if (idx < n) dst[idx] = f2bf(src[idx]);
}

// Pack per-layer QKV weights into Bt layout [1536][512] (hi, optional lo):
// row n: which=n>>9, h=(n>>6)&7, d=n&63 ; Bt[n][k] = W_which[h][k][d]
__global__ void conv_qkvw_kernel(const float* __restrict__ wq,
                                 const float* __restrict__ wk,
                                 const float* __restrict__ wv,
                                 ushort_t* __restrict__ hi,
                                 ushort_t* __restrict__ lo) {
    int idx = blockIdx.x * 256 + threadIdx.x;   // over 1536*512
    int n = idx >> 9, k = idx & 511;
    int which = n >> 9, h = (n >> 6) & 7, d = n & 63;
    const float* W = (which == 0) ? wq : (which == 1) ? wk : wv;
    float v = W[((size_t)h * D_MODEL + k) * D_HEAD + d];
    ushort_t hv = f2bf(v);
    hi[idx] = hv;
    if (lo) lo[idx] = f2bf(v - bf2f(hv));
}

// ---------------------------------------------------------------- MFMA GEMM
// C[M,N] = A[M,K] @ Bt[N,K]^T ; A,Bt bf16 row-major, acc fp32.
// Block: 256 thr = 4 waves, tile 64x64, wave tile 32x32 (2x2 of 16x16x32).
// MODE 0: scatter fp32 to Q|K|V buffers in [h][tok][64] layout (N=1536)
// MODE 1: +bias, relu, bf16 out [M,N]
// MODE 2: +bias, fp32 out [M,N]
template<int MODE>
__global__ __launch_bounds__(256, 2)
void gemm_kernel(const ushort_t* __restrict__ A, const ushort_t* __restrict__ Bt,
                 const float* __restrict__ bias, float* __restrict__ outF,
                 ushort_t* __restrict__ outB, int M, int N, int K) {
    __shared__ ushort_t As[64][72];   // +8 pad: keeps 16B align, breaks bank alias
    __shared__ ushort_t Bs[64][72];
    const int tid = threadIdx.x;
    const int m0 = blockIdx.y * 64, n0 = blockIdx.x * 64;
    const int w = tid >> 6, lane = tid & 63;
    const int wm = (w >> 1) * 32, wn = (w & 1) * 32;
    const int col = lane & 15, quad = lane >> 4;

    f32x4 acc[2][2] = {};

    for (int k0 = 0; k0 < K; k0 += 64) {
        __syncthreads();
#pragma unroll
        for (int p = 0; p < 2; p++) {
            int idx = p * 256 + tid;          // 512 tasks: 64 rows x 8 chunks
            int row = idx >> 3, ch = (idx & 7) * 8;
            *(uint4*)(&As[row][ch]) =
                *(const uint4*)(A + (size_t)(m0 + row) * K + k0 + ch);
            *(uint4*)(&Bs[row][ch]) =
                *(const uint4*)(Bt + (size_t)(n0 + row) * K + k0 + ch);
        }
        __syncthreads();
#pragma unroll
        for (int ks = 0; ks < 64; ks += 32) {
            bf16x8 af[2], bf[2];
#pragma unroll
            for (int t = 0; t < 2; t++) {
                af[t] = *(const bf16x8*)(&As[wm + t * 16 + col][ks + quad * 8]);
                bf[t] = *(const bf16x8*)(&Bs[wn + t * 16 + col][ks + quad * 8]);
            }
#pragma unroll
            for (int mt = 0; mt < 2; mt++)
#pragma unroll
                for (int nt = 0; nt < 2; nt++)
                    acc[mt][nt] = __builtin_amdgcn_mfma_f32_16x16x32_bf16(
                        af[mt], bf[nt], acc[mt][nt], 0, 0, 0);
        }
    }

#pragma unroll
    for (int mt = 0; mt < 2; mt++) {
#pragma unroll
        for (int nt = 0; nt < 2; nt++) {
            int n = n0 + wn + nt * 16 + col;
#pragma unroll
            for (int r = 0; r < 4; r++) {
                int m = m0 + wm + mt * 16 + quad * 4 + r;
                float v = acc[mt][nt][r];
                if (MODE == 0) {
                    int which = n >> 9, hd = n & 511;
                    outF[(size_t)which * (size_t)NTOK * D_MODEL
                         + (size_t)(((hd >> 6) * NTOK + m) << 6) + (hd & 63)] = v;
                } else if (MODE == 1) {
                    float t = fmaxf(v + bias[n], 0.f);
                    outB[(size_t)m * N + n] = f2bf(t);
                } else {
                    outF[(size_t)m * N + n] = v + bias[n];
                }
            }
        }
    }
}

// ---------------------------------------------------------------- hi/lo GEMM
// High-precision bf16 GEMM for layer-1 QKV: A fp32 split in-kernel into
// hi+lo bf16; Bt pre-split (hi,lo). acc = Ah*Bh + Ah*Bl + Al*Bh  (~1e-5 rel).
// Epilogue = MODE 0 scatter (fp32 Q|K|V).
__global__ __launch_bounds__(256, 2)
void gemm_hilo_kernel(const float* __restrict__ A,
                      const ushort_t* __restrict__ Bh,
                      const ushort_t* __restrict__ Bl,
                      float* __restrict__ outF, int M, int N, int K) {
    __shared__ ushort_t Ash[64][72];
    __shared__ ushort_t Asl[64][72];
    __shared__ ushort_t Bsh[64][72];
    __shared__ ushort_t Bsl[64][72];
    const int tid = threadIdx.x;
    const int m0 = blockIdx.y * 64, n0 = blockIdx.x * 64;
    const int w = tid >> 6, lane = tid & 63;
    const int wm = (w >> 1) * 32, wn = (w & 1) * 32;
    const int col = lane & 15, quad = lane >> 4;

    f32x4 acc[2][2] = {};

    for (int k0 = 0; k0 < K; k0 += 64) {
        __syncthreads();
#pragma unroll
        for (int p = 0; p < 4; p++) {
            int idx = p * 256 + tid;
            int row = idx >> 4, c4 = (idx & 15) * 4;
            float4 v = *(const float4*)(A + (size_t)(m0 + row) * K + k0 + c4);
            ushort_t h0 = f2bf(v.x), h1 = f2bf(v.y), h2 = f2bf(v.z), h3 = f2bf(v.w);
            *(ushort4*)(&Ash[row][c4]) = make_ushort4(h0, h1, h2, h3);
            *(ushort4*)(&Asl[row][c4]) = make_ushort4(
                f2bf(v.x - bf2f(h0)), f2bf(v.y - bf2f(h1)),
                f2bf(v.z - bf2f(h2)), f2bf(v.w - bf2f(h3)));
        }
#pragma unroll
        for (int p = 0; p < 2; p++) {
            int idx = p * 256 + tid;
            int row = idx >> 3, ch = (idx & 7) * 8;
            *(uint4*)(&Bsh[row][ch]) =
                *(const uint4*)(Bh + (size_t)(n0 + row) * K + k0 + ch);
            *(uint4*)(&Bsl[row][ch]) =
                *(const uint4*)(Bl + (size_t)(n0 + row) * K + k0 + ch);
        }
        __syncthreads();
#pragma unroll
        for (int ks = 0; ks < 64; ks += 32) {
            bf16x8 ah[2], al[2], bh[2], bl[2];
#pragma unroll
            for (int t = 0; t < 2; t++) {
                ah[t] = *(const bf16x8*)(&Ash[wm + t * 16 + col][ks + quad * 8]);
                al[t] = *(const bf16x8*)(&Asl[wm + t * 16 + col][ks + quad * 8]);
                bh[t] = *(const bf16x8*)(&Bsh[wn + t * 16 + col][ks + quad * 8]);
                bl[t] = *(const bf16x8*)(&Bsl[wn + t * 16 + col][ks + quad * 8]);
            }
#pragma unroll
            for (int mt = 0; mt < 2; mt++)
#pragma unroll
                for (int nt = 0; nt < 2; nt++) {
                    acc[mt][nt] = __builtin_amdgcn_mfma_f32_16x16x32_bf16(
                        ah[mt], bh[nt], acc[mt][nt], 0, 0, 0);
                    acc[mt][nt] = __builtin_amdgcn_mfma_f32_16x16x32_bf16(
                        ah[mt], bl[nt], acc[mt][nt], 0, 0, 0);
                    acc[mt][nt] = __builtin_amdgcn_mfma_f32_16x16x32_bf16(
                        al[mt], bh[nt], acc[mt][nt], 0, 0, 0);
                }
        }
    }

#pragma unroll
    for (int mt = 0; mt < 2; mt++) {
#pragma unroll
        for (int nt = 0; nt < 2; nt++) {
            int n = n0 + wn + nt * 16 + col;
            int which = n >> 9, hd = n & 511;
#pragma unroll
            for (int r = 0; r < 4; r++) {
                int m = m0 + wm + mt * 16 + quad * 4 + r;
                outF[(size_t)which * (size_t)NTOK * D_MODEL
                     + (size_t)(((hd >> 6) * NTOK + m) << 6) + (hd & 63)]
                    = acc[mt][nt][r];
            }
        }
    }
}

// ---------------------------------------------------------------- attention
// MFMA flash attention. Block = 64 Q-rows of one (b,h); wave w owns rows
// w*16..w*16+15. Per 64-key tile: K staged hi/lo bf16 (fp32 split -> layer-1
// scores effectively fp32), V staged transposed bf16. S via 6 MFMAs per
// 16-key group (hi/lo), online softmax in C-layout (quad shfl_xor reductions),
// P -> per-wave LDS -> A-layout frags -> PV MFMA.
__global__ __launch_bounds__(256, 4)
void attention_kernel(const float* __restrict__ Q,
                      const float* __restrict__ K,
                      const float* __restrict__ V,
                      float* __restrict__ O) {
    const int qt = blockIdx.x, b = blockIdx.y, h = blockIdx.z;
    const int tid = threadIdx.x;
    const int w = tid >> 6, lane = tid & 63;
    const int col = lane & 15, quad = lane >> 4;
    const int hb = h * BATCH + b;
    const size_t base = (size_t)hb * SEQ * D_HEAD;

    __shared__ ushort_t Kh[64][72];    // 9 KB each
    __shared__ ushort_t Kl[64][72];
    __shared__ ushort_t Vt[64][72];    // V transposed [dim][key]
    __shared__ ushort_t Pl[4][16][72]; // per-wave P tile [qrow][key]

    // Q fragments hi/lo for rows w*16+col (A-layout: m=lane&15, k=quad*8+j)
    bf16x8 qh[2], ql[2];
    {
        const float* qrow = Q + base + (size_t)(qt * 64 + w * 16 + col) * D_HEAD;
#pragma unroll
        for (int kh = 0; kh < 2; kh++) {
            const float4* qp = (const float4*)(qrow + kh * 32 + quad * 8);
            float4 aa = qp[0], bb = qp[1];
            float v[8] = {aa.x, aa.y, aa.z, aa.w, bb.x, bb.y, bb.z, bb.w};
#pragma unroll
            for (int j = 0; j < 8; j++) {
                ushort_t hv = f2bf(v[j]);
                qh[kh][j] = (short)hv;
                ql[kh][j] = (short)f2bf(v[j] - bf2f(hv));
            }
        }
    }

    f32x4 acco[4] = {};
    float mrun[4], lrun[4];
#pragma unroll
    for (int r = 0; r < 4; r++) { mrun[r] = -1e30f; lrun[r] = 0.f; }
    const float inv_temper = 0.04419417382415922f;  // 1/sqrt(512)

    for (int t0 = 0; t0 < SEQ; t0 += 64) {
        __syncthreads();   // prev tile's reads done before restage
#pragma unroll
        for (int i = 0; i < 4; i++) {
            int idx = i * 256 + tid;            // 1024 float4 tasks: 64 keys x 16
            int key = idx >> 4, d4 = (idx & 15) * 4;
            float4 kv = *(const float4*)(K + base + (size_t)(t0 + key) * D_HEAD + d4);
            ushort_t h0 = f2bf(kv.x), h1 = f2bf(kv.y), h2 = f2bf(kv.z), h3 = f2bf(kv.w);
            *(ushort4*)(&Kh[key][d4]) = make_ushort4(h0, h1, h2, h3);
            *(ushort4*)(&Kl[key][d4]) = make_ushort4(
                f2bf(kv.x - bf2f(h0)), f2bf(kv.y - bf2f(h1)),
                f2bf(kv.z - bf2f(h2)), f2bf(kv.w - bf2f(h3)));
            float4 vv = *(const float4*)(V + base + (size_t)(t0 + key) * D_HEAD + d4);
            Vt[d4 + 0][key] = f2bf(vv.x);
            Vt[d4 + 1][key] = f2bf(vv.y);
            Vt[d4 + 2][key] = f2bf(vv.z);
            Vt[d4 + 3][key] = f2bf(vv.w);
        }
        __syncthreads();

        // S = Q K^T (hi/lo), keys nt*16+col, rows quad*4+r
        float sc[4][4];
#pragma unroll
        for (int nt = 0; nt < 4; nt++) {
            bf16x8 bh0 = *(const bf16x8*)(&Kh[nt * 16 + col][quad * 8]);
            bf16x8 bh1 = *(const bf16x8*)(&Kh[nt * 16 + col][32 + quad * 8]);
            bf16x8 bl0 = *(const bf16x8*)(&Kl[nt * 16 + col][quad * 8]);
            bf16x8 bl1 = *(const bf16x8*)(&Kl[nt * 16 + col][32 + quad * 8]);
            f32x4 s = {};
            s = __builtin_amdgcn_mfma_f32_16x16x32_bf16(qh[0], bh0, s, 0, 0, 0);
            s = __builtin_amdgcn_mfma_f32_16x16x32_bf16(qh[1], bh1, s, 0, 0, 0);
            s = __builtin_amdgcn_mfma_f32_16x16x32_bf16(qh[0], bl0, s, 0, 0, 0);
            s = __builtin_amdgcn_mfma_f32_16x16x32_bf16(qh[1], bl1, s, 0, 0, 0);
            s = __builtin_amdgcn_mfma_f32_16x16x32_bf16(ql[0], bh0, s, 0, 0, 0);
            s = __builtin_amdgcn_mfma_f32_16x16x32_bf16(ql[1], bh1, s, 0, 0, 0);
#pragma unroll
            for (int r = 0; r < 4; r++) sc[nt][r] = s[r] * inv_temper;
        }

        // row stats across the 16 lanes of each quad (cols) and 4 nt groups
        float tmax[4];
#pragma unroll
        for (int r = 0; r < 4; r++)
            tmax[r] = fmaxf(fmaxf(sc[0][r], sc[1][r]), fmaxf(sc[2][r], sc[3][r]));
#pragma unroll
        for (int mask = 1; mask < 16; mask <<= 1)
#pragma unroll
            for (int r = 0; r < 4; r++)
                tmax[r] = fmaxf(tmax[r], __shfl_xor(tmax[r], mask, 64));

        float alpha[4], tsum[4];
#pragma unroll
        for (int r = 0; r < 4; r++) {
            float mn = fmaxf(mrun[r], tmax[r]);
            alpha[r] = __expf(mrun[r] - mn);
            mrun[r] = mn;
            tsum[r] = 0.f;
        }
#pragma unroll
        for (int nt = 0; nt < 4; nt++)
#pragma unroll
            for (int r = 0; r < 4; r++) {
                float pv = __expf(sc[nt][r] - mrun[r]);
                tsum[r] += pv;
                Pl[w][quad * 4 + r][nt * 16 + col] = f2bf(pv);
            }
#pragma unroll
        for (int mask = 1; mask < 16; mask <<= 1)
#pragma unroll
            for (int r = 0; r < 4; r++)
                tsum[r] += __shfl_xor(tsum[r], mask, 64);
#pragma unroll
        for (int r = 0; r < 4; r++)
            lrun[r] = lrun[r] * alpha[r] + tsum[r];
#pragma unroll
        for (int nt = 0; nt < 4; nt++)
#pragma unroll
            for (int r = 0; r < 4; r++)
                acco[nt][r] *= alpha[r];

        __syncthreads();   // Pl writes visible (wave-local need, barrier is safe)

        // P (A-layout) and PV
        bf16x8 ap0 = *(const bf16x8*)(&Pl[w][col][quad * 8]);
        bf16x8 ap1 = *(const bf16x8*)(&Pl[w][col][32 + quad * 8]);
#pragma unroll
        for (int nt = 0; nt < 4; nt++) {
            bf16x8 bv0 = *(const bf16x8*)(&Vt[nt * 16 + col][quad * 8]);
            bf16x8 bv1 = *(const bf16x8*)(&Vt[nt * 16 + col][32 + quad * 8]);
            acco[nt] = __builtin_amdgcn_mfma_f32_16x16x32_bf16(ap0, bv0, acco[nt], 0, 0, 0);
            acco[nt] = __builtin_amdgcn_mfma_f32_16x16x32_bf16(ap1, bv1, acco[nt], 0, 0, 0);
        }
    }

    // epilogue: O[b][row][h*64 + dim], dim = nt*16+col, row = qt*64+w*16+quad*4+r
#pragma unroll
    for (int nt = 0; nt < 4; nt++) {
#pragma unroll
        for (int r = 0; r < 4; r++) {
            int row = qt * 64 + w * 16 + quad * 4 + r;
            O[((size_t)b * SEQ + row) * D_MODEL + h * D_HEAD + nt * 16 + col]
                = acco[nt][r] / lrun[r];
        }
    }
}

// ---------------------------------------------------------------- add + LN
__device__ inline float block_sum_256(float v, float* tmp) {
#pragma unroll
    for (int off = 32; off > 0; off >>= 1) v += __shfl_down(v, off, 64);
    if ((threadIdx.x & 63) == 0) tmp[threadIdx.x >> 6] = v;
    __syncthreads();
    return tmp[0] + tmp[1] + tmp[2] + tmp[3];
}

// Writes fp32 Out AND bf16 OutBf. Safe for Out==R (in-place).
__global__ void add_norm_kernel(const float* __restrict__ A,
                                const float* __restrict__ R,
                                const float* __restrict__ ga,
                                const float* __restrict__ gb,
                                float* __restrict__ Out,
                                ushort_t* __restrict__ OutBf) {
    int tok = blockIdx.x, tid = threadIdx.x;
    __shared__ float t1[4], t2[4];
    size_t base = (size_t)tok * D_MODEL;
    float z0 = A[base + tid]       + R[base + tid];
    float z1 = A[base + tid + 256] + R[base + tid + 256];
    float s = block_sum_256(z0 + z1, t1);
    float mu = s * (1.f / (float)D_MODEL);
    float d0 = z0 - mu, d1 = z1 - mu;
    float ss = block_sum_256(d0 * d0 + d1 * d1, t2);
    float sigma = sqrtf(ss * (1.f / (float)(D_MODEL - 1)));
    float inv = 1.f / (sigma + LN_EPS);
    float r0 = d0 * inv * ga[tid]       + gb[tid];
    float r1 = d1 * inv * ga[tid + 256] + gb[tid + 256];
    Out[base + tid]         = r0;
    Out[base + tid + 256]   = r1;
    OutBf[base + tid]       = f2bf(r0);
    OutBf[base + tid + 256] = f2bf(r1);
}

// ---------------------------------------------------------------- launch
extern "C" void kernel_launch(void* const* d_in, const int* in_sizes, int n_in,
                              void* d_out, int out_size, void* d_ws, size_t ws_size,
                              hipStream_t stream) {
    const float* x     = (const float*)d_in[0];
    const float* pe    = (const float*)d_in[1];
    const float* w_qs  = (const float*)d_in[2];
    const float* w_ks  = (const float*)d_in[3];
    const float* w_vs  = (const float*)d_in[4];
    const float* ln1_a = (const float*)d_in[5];
    const float* ln1_b = (const float*)d_in[6];
    const float* w1    = (const float*)d_in[7];
    const float* b1    = (const float*)d_in[8];
    const float* w2    = (const float*)d_in[9];
    const float* b2    = (const float*)d_in[10];
    const float* ln2_a = (const float*)d_in[11];
    const float* ln2_b = (const float*)d_in[12];
    float* out = (float*)d_out;

    const size_t NXD = (size_t)NTOK * D_MODEL;       // 2M elements
    char* p = (char*)d_ws;
    float*    X    = (float*)p;     p += NXD * 4;                 // 8 MB
    float*    Ob   = (float*)p;     p += NXD * 4;                 // 8 MB
    ushort_t* Xbf  = (ushort_t*)p;  p += NXD * 2;                 // 4 MB
    float*    QKVf = (float*)p;     p += 3 * NXD * 4;             // 24 MB (Q|K|V fp32)
    ushort_t* Wqkv = (ushort_t*)p;  p += (size_t)N_LAYERS * 1536 * 512 * 2;  // 3 MB (hi)
    ushort_t* WqkvL= (ushort_t*)p;  p += (size_t)1536 * 512 * 2;  // 1.5 MB (lo, layer 0)
    ushort_t* W1b  = (ushort_t*)p;  p += (size_t)N_LAYERS * D_INNER * D_MODEL * 2;  // 2 MB
    ushort_t* W2b  = (ushort_t*)p;  /* 2 MB */
    // H (bf16, 8 MB) aliases QKVf: dead ranges don't overlap in time.
    ushort_t* Hbf  = (ushort_t*)QKVf;

    add_pos_kernel<<<(int)(NXD / 256), 256, 0, stream>>>(x, pe, X);

    for (int i = 0; i < N_LAYERS; i++) {
        conv_qkvw_kernel<<<1536 * 512 / 256, 256, 0, stream>>>(
            w_qs + (size_t)i * N_HEAD * D_MODEL * D_HEAD,
            w_ks + (size_t)i * N_HEAD * D_MODEL * D_HEAD,
            w_vs + (size_t)i * N_HEAD * D_MODEL * D_HEAD,
            Wqkv + (size_t)i * 1536 * 512,
            (i == 0) ? WqkvL : (ushort_t*)nullptr);
    }
    conv_bf16_kernel<<<(N_LAYERS * D_INNER * D_MODEL) / 256, 256, 0, stream>>>(
        w1, W1b, N_LAYERS * D_INNER * D_MODEL);
    conv_bf16_kernel<<<(N_LAYERS * D_MODEL * D_INNER) / 256, 256, 0, stream>>>(
        w2, W2b, N_LAYERS * D_MODEL * D_INNER);

    float* Qb = QKVf;
    float* Kb = QKVf + NXD;
    float* Vb = QKVf + 2 * NXD;

    for (int i = 0; i < N_LAYERS; i++) {
        // QKV: M=4096, N=1536, K=512
        if (i == 0) {
            gemm_hilo_kernel<<<dim3(1536 / 64, NTOK / 64), 256, 0, stream>>>(
                X, Wqkv, WqkvL, QKVf, NTOK, 1536, D_MODEL);
        } else {
            gemm_kernel<0><<<dim3(1536 / 64, NTOK / 64), 256, 0, stream>>>(
                Xbf, Wqkv + (size_t)i * 1536 * 512, nullptr, QKVf, nullptr,
                NTOK, 1536, D_MODEL);
        }

        attention_kernel<<<dim3(SEQ / 64, BATCH, N_HEAD), 256, 0, stream>>>(
            Qb, Kb, Vb, Ob);

        add_norm_kernel<<<NTOK, 256, 0, stream>>>(
            Ob, X, ln1_a + i * D_MODEL, ln1_b + i * D_MODEL, X, Xbf);

        // FFN1: M=4096, N=1024, K=512, bias+relu -> bf16 H (aliases QKVf)
        gemm_kernel<1><<<dim3(D_INNER / 64, NTOK / 64), 256, 0, stream>>>(
            Xbf, W1b + (size_t)i * D_INNER * D_MODEL, b1 + (size_t)i * D_INNER,
            nullptr, Hbf, NTOK, D_INNER, D_MODEL);

        // FFN2: M=4096, N=512, K=1024, bias -> fp32 Ob
        gemm_kernel<2><<<dim3(D_MODEL / 64, NTOK / 64), 256, 0, stream>>>(
            Hbf, W2b + (size_t)i * D_MODEL * D_INNER, b2 + (size_t)i * D_MODEL,
            Ob, nullptr, NTOK, D_MODEL, D_INNER);

        float* dst = (i == N_LAYERS - 1) ? out : X;
        add_norm_kernel<<<NTOK, 256, 0, stream>>>(
            Ob, X, ln2_a + i * D_MODEL, ln2_b + i * D_MODEL, dst, Xbf);
    }
}

// Round 7
// 388.238 us; speedup vs baseline: 12.2348x; 1.0956x over previous
//
#include <hip/hip_runtime.h>
#include <math.h>

#define D_MODEL 512
#define SEQ     1024
#define BATCH   4
#define N_LAYERS 2
#define N_HEAD  8
#define D_HEAD  64
#define D_INNER 1024
#define NTOK    (BATCH*SEQ)   // 4096
#define LN_EPS  1e-3f

typedef float f32x4 __attribute__((ext_vector_type(4)));
typedef short bf16x8 __attribute__((ext_vector_type(8)));
typedef unsigned short ushort_t;
typedef unsigned int uint_t;
typedef unsigned long long ull_t;

// fp32 -> bf16 round-to-nearest-even
__device__ inline ushort_t f2bf(float f) {
    uint_t u = __float_as_uint(f);
    u += 0x7FFFu + ((u >> 16) & 1u);
    return (ushort_t)(u >> 16);
}
__device__ inline float bf2f(ushort_t h) {
    return __uint_as_float((uint_t)h << 16);
}

// ---------------------------------------------------------------- add pos enc
__global__ void add_pos_kernel(const float* __restrict__ x,
                               const float* __restrict__ pe,
                               float* __restrict__ X) {
    int idx = blockIdx.x * blockDim.x + threadIdx.x;   // over NTOK*D_MODEL
    int l = (idx / D_MODEL) % SEQ;
    int d = idx % D_MODEL;
    X[idx] = x[idx] + pe[l * D_MODEL + d];
}

// ---------------------------------------------------------------- weight conv
__global__ void conv_bf16_kernel(const float* __restrict__ src,
                                 ushort_t* __restrict__ dst, int n) {
    int idx = blockIdx.x * 256 + threadIdx.x;
    if (idx < n) dst[idx] = f2bf(src[idx]);
}

// Pack per-layer QKV weights into Bt layout [1536][512] (hi, optional lo):
// row n: which=n>>9, h=(n>>6)&7, d=n&63 ; Bt[n][k] = W_which[h][k][d]
__global__ void conv_qkvw_kernel(const float* __restrict__ wq,
                                 const float* __restrict__ wk,
                                 const float* __restrict__ wv,
                                 ushort_t* __restrict__ hi,
                                 ushort_t* __restrict__ lo) {
    int idx = blockIdx.x * 256 + threadIdx.x;   // over 1536*512
    int n = idx >> 9, k = idx & 511;
    int which = n >> 9, h = (n >> 6) & 7, d = n & 63;
    const float* W = (which == 0) ? wq : (which == 1) ? wk : wv;
    float v = W[((size_t)h * D_MODEL + k) * D_HEAD + d];
    ushort_t hv = f2bf(v);
    hi[idx] = hv;
    if (lo) lo[idx] = f2bf(v - bf2f(hv));
}

// ---------------------------------------------------------------- QKV scatter
// n in [0,1536): which=n>>9 (0:Q 1:K 2:V), head=(n>>6)&7, d=n&63.
// Q,K -> hi/lo bf16 [hb][seq][64]; V -> bf16 transposed [hb][dim][seq].
// m_base = first of 4 consecutive token rows (aligned 4, same batch).
__device__ inline void qkv_scatter(f32x4 a, int n, int m_base,
                                   ushort_t* Qhi, ushort_t* Qlo,
                                   ushort_t* Khi, ushort_t* Klo,
                                   ushort_t* Vt) {
    int which = n >> 9, hd = n & 511;
    int head = hd >> 6, d = hd & 63;
    int hb = head * BATCH + (m_base >> 10);
    int l  = m_base & 1023;
    if (which == 2) {
        ushort4 pk = make_ushort4(f2bf(a[0]), f2bf(a[1]), f2bf(a[2]), f2bf(a[3]));
        *(ushort4*)(Vt + ((size_t)hb * D_HEAD + d) * SEQ + l) = pk;
    } else {
        ushort_t* H = (which == 0) ? Qhi : Khi;
        ushort_t* L = (which == 0) ? Qlo : Klo;
#pragma unroll
        for (int r = 0; r < 4; r++) {
            float v = a[r];
            ushort_t hv = f2bf(v);
            size_t off = ((size_t)hb * SEQ + l + r) * D_HEAD + d;
            H[off] = hv;
            L[off] = f2bf(v - bf2f(hv));
        }
    }
}

// ---------------------------------------------------------------- MFMA GEMM
// C[M,N] = A[M,K] @ Bt[N,K]^T ; A,Bt bf16 row-major, acc fp32.
// Block: 256 thr = 4 waves, tile 64x64, wave tile 32x32 (2x2 of 16x16x32).
// MODE 0: qkv_scatter epilogue  MODE 1: +bias, relu, bf16 out  MODE 2: +bias, fp32 out
template<int MODE>
__global__ __launch_bounds__(256, 2)
void gemm_kernel(const ushort_t* __restrict__ A, const ushort_t* __restrict__ Bt,
                 const float* __restrict__ bias, float* __restrict__ outF,
                 ushort_t* __restrict__ outB,
                 ushort_t* __restrict__ Qhi, ushort_t* __restrict__ Qlo,
                 ushort_t* __restrict__ Khi, ushort_t* __restrict__ Klo,
                 ushort_t* __restrict__ Vt,
                 int M, int N, int K) {
    __shared__ ushort_t As[64][72];   // +8 pad: keeps 16B align, breaks bank alias
    __shared__ ushort_t Bs[64][72];
    const int tid = threadIdx.x;
    const int m0 = blockIdx.y * 64, n0 = blockIdx.x * 64;
    const int w = tid >> 6, lane = tid & 63;
    const int wm = (w >> 1) * 32, wn = (w & 1) * 32;
    const int col = lane & 15, quad = lane >> 4;

    f32x4 acc[2][2] = {};

    for (int k0 = 0; k0 < K; k0 += 64) {
        __syncthreads();
#pragma unroll
        for (int p = 0; p < 2; p++) {
            int idx = p * 256 + tid;          // 512 tasks: 64 rows x 8 chunks
            int row = idx >> 3, ch = (idx & 7) * 8;
            *(uint4*)(&As[row][ch]) =
                *(const uint4*)(A + (size_t)(m0 + row) * K + k0 + ch);
            *(uint4*)(&Bs[row][ch]) =
                *(const uint4*)(Bt + (size_t)(n0 + row) * K + k0 + ch);
        }
        __syncthreads();
#pragma unroll
        for (int ks = 0; ks < 64; ks += 32) {
            bf16x8 af[2], bf[2];
#pragma unroll
            for (int t = 0; t < 2; t++) {
                af[t] = *(const bf16x8*)(&As[wm + t * 16 + col][ks + quad * 8]);
                bf[t] = *(const bf16x8*)(&Bs[wn + t * 16 + col][ks + quad * 8]);
            }
#pragma unroll
            for (int mt = 0; mt < 2; mt++)
#pragma unroll
                for (int nt = 0; nt < 2; nt++)
                    acc[mt][nt] = __builtin_amdgcn_mfma_f32_16x16x32_bf16(
                        af[mt], bf[nt], acc[mt][nt], 0, 0, 0);
        }
    }

#pragma unroll
    for (int mt = 0; mt < 2; mt++) {
#pragma unroll
        for (int nt = 0; nt < 2; nt++) {
            int n = n0 + wn + nt * 16 + col;
            int m_base = m0 + wm + mt * 16 + quad * 4;
            if (MODE == 0) {
                qkv_scatter(acc[mt][nt], n, m_base, Qhi, Qlo, Khi, Klo, Vt);
            } else {
#pragma unroll
                for (int r = 0; r < 4; r++) {
                    int m = m_base + r;
                    float v = acc[mt][nt][r];
                    if (MODE == 1) {
                        float t = fmaxf(v + bias[n], 0.f);
                        outB[(size_t)m * N + n] = f2bf(t);
                    } else {
                        outF[(size_t)m * N + n] = v + bias[n];
                    }
                }
            }
        }
    }
}

// ---------------------------------------------------------------- hi/lo GEMM
// High-precision bf16 GEMM for layer-1 QKV: A fp32 split in-kernel into
// hi+lo bf16; Bt pre-split (hi,lo). acc = Ah*Bh + Ah*Bl + Al*Bh  (~1e-5 rel).
__global__ __launch_bounds__(256, 2)
void gemm_hilo_kernel(const float* __restrict__ A,
                      const ushort_t* __restrict__ Bh,
                      const ushort_t* __restrict__ Bl,
                      ushort_t* __restrict__ Qhi, ushort_t* __restrict__ Qlo,
                      ushort_t* __restrict__ Khi, ushort_t* __restrict__ Klo,
                      ushort_t* __restrict__ Vt,
                      int M, int N, int K) {
    __shared__ ushort_t Ash[64][72];
    __shared__ ushort_t Asl[64][72];
    __shared__ ushort_t Bsh[64][72];
    __shared__ ushort_t Bsl[64][72];
    const int tid = threadIdx.x;
    const int m0 = blockIdx.y * 64, n0 = blockIdx.x * 64;
    const int w = tid >> 6, lane = tid & 63;
    const int wm = (w >> 1) * 32, wn = (w & 1) * 32;
    const int col = lane & 15, quad = lane >> 4;

    f32x4 acc[2][2] = {};

    for (int k0 = 0; k0 < K; k0 += 64) {
        __syncthreads();
#pragma unroll
        for (int p = 0; p < 4; p++) {
            int idx = p * 256 + tid;
            int row = idx >> 4, c4 = (idx & 15) * 4;
            float4 v = *(const float4*)(A + (size_t)(m0 + row) * K + k0 + c4);
            ushort_t h0 = f2bf(v.x), h1 = f2bf(v.y), h2 = f2bf(v.z), h3 = f2bf(v.w);
            *(ushort4*)(&Ash[row][c4]) = make_ushort4(h0, h1, h2, h3);
            *(ushort4*)(&Asl[row][c4]) = make_ushort4(
                f2bf(v.x - bf2f(h0)), f2bf(v.y - bf2f(h1)),
                f2bf(v.z - bf2f(h2)), f2bf(v.w - bf2f(h3)));
        }
#pragma unroll
        for (int p = 0; p < 2; p++) {
            int idx = p * 256 + tid;
            int row = idx >> 3, ch = (idx & 7) * 8;
            *(uint4*)(&Bsh[row][ch]) =
                *(const uint4*)(Bh + (size_t)(n0 + row) * K + k0 + ch);
            *(uint4*)(&Bsl[row][ch]) =
                *(const uint4*)(Bl + (size_t)(n0 + row) * K + k0 + ch);
        }
        __syncthreads();
#pragma unroll
        for (int ks = 0; ks < 64; ks += 32) {
            bf16x8 ah[2], al[2], bh[2], bl[2];
#pragma unroll
            for (int t = 0; t < 2; t++) {
                ah[t] = *(const bf16x8*)(&Ash[wm + t * 16 + col][ks + quad * 8]);
                al[t] = *(const bf16x8*)(&Asl[wm + t * 16 + col][ks + quad * 8]);
                bh[t] = *(const bf16x8*)(&Bsh[wn + t * 16 + col][ks + quad * 8]);
                bl[t] = *(const bf16x8*)(&Bsl[wn + t * 16 + col][ks + quad * 8]);
            }
#pragma unroll
            for (int mt = 0; mt < 2; mt++)
#pragma unroll
                for (int nt = 0; nt < 2; nt++) {
                    acc[mt][nt] = __builtin_amdgcn_mfma_f32_16x16x32_bf16(
                        ah[mt], bh[nt], acc[mt][nt], 0, 0, 0);
                    acc[mt][nt] = __builtin_amdgcn_mfma_f32_16x16x32_bf16(
                        ah[mt], bl[nt], acc[mt][nt], 0, 0, 0);
                    acc[mt][nt] = __builtin_amdgcn_mfma_f32_16x16x32_bf16(
                        al[mt], bh[nt], acc[mt][nt], 0, 0, 0);
                }
        }
    }

#pragma unroll
    for (int mt = 0; mt < 2; mt++)
#pragma unroll
        for (int nt = 0; nt < 2; nt++)
            qkv_scatter(acc[mt][nt], n0 + wn + nt * 16 + col,
                        m0 + wm + mt * 16 + quad * 4, Qhi, Qlo, Khi, Klo, Vt);
}

// ---------------------------------------------------------------- attention
// MFMA flash attention, precomputed bf16 operands.
// Block = 64 Q-rows of one (b,h); wave w owns rows w*16..w*16+15.
// XCD swizzle: all 16 Q-tiles of one hb land on one XCD (K/V L2-resident).
// Staging = pure uint4 copies (K hi/lo [seq][64], V^T [dim][seq]).
__global__ __launch_bounds__(256, 2)
void attention_kernel(const ushort_t* __restrict__ Qhi,
                      const ushort_t* __restrict__ Qlo,
                      const ushort_t* __restrict__ Khi,
                      const ushort_t* __restrict__ Klo,
                      const ushort_t* __restrict__ Vt,
                      float* __restrict__ O) {
    const int bid = blockIdx.x;          // 512
    const int j   = bid >> 3;
    const int hb  = (bid & 7) * 4 + (j >> 4);
    const int qt  = j & 15;
    const int h = hb >> 2, b = hb & 3;
    const int tid = threadIdx.x;
    const int w = tid >> 6, lane = tid & 63;
    const int col = lane & 15, quad = lane >> 4;
    const size_t kbase = (size_t)hb * SEQ * D_HEAD;
    const size_t vbase = (size_t)hb * D_HEAD * SEQ;

    __shared__ ushort_t Kh[64][72];
    __shared__ ushort_t Kl[64][72];
    __shared__ ushort_t Vs[64][72];     // V^T tile [dim][key]
    __shared__ ushort_t Pl[4][16][68];  // per-wave P [qrow][key], stride 68

    // Q fragments hi/lo (A-layout) straight from global
    bf16x8 qh[2], ql[2];
    {
        const ushort_t* qp = Qhi + kbase + (size_t)(qt * 64 + w * 16 + col) * D_HEAD;
        const ushort_t* lp = Qlo + kbase + (size_t)(qt * 64 + w * 16 + col) * D_HEAD;
        qh[0] = *(const bf16x8*)(qp + quad * 8);
        qh[1] = *(const bf16x8*)(qp + 32 + quad * 8);
        ql[0] = *(const bf16x8*)(lp + quad * 8);
        ql[1] = *(const bf16x8*)(lp + 32 + quad * 8);
    }

    f32x4 acco[4] = {};
    float mrun[4], lrun[4];
#pragma unroll
    for (int r = 0; r < 4; r++) { mrun[r] = -1e30f; lrun[r] = 0.f; }
    const float inv_temper = 0.04419417382415922f;  // 1/sqrt(512)

    for (int t0 = 0; t0 < SEQ; t0 += 64) {
        __syncthreads();   // prev tile's reads done before restage
#pragma unroll
        for (int p = 0; p < 2; p++) {
            int idx = p * 256 + tid;          // 512 tasks: 64 rows x 8 chunks
            int row = idx >> 3, ch = (idx & 7) * 8;
            *(uint4*)(&Kh[row][ch]) =
                *(const uint4*)(Khi + kbase + (size_t)(t0 + row) * D_HEAD + ch);
            *(uint4*)(&Kl[row][ch]) =
                *(const uint4*)(Klo + kbase + (size_t)(t0 + row) * D_HEAD + ch);
            *(uint4*)(&Vs[row][ch]) =
                *(const uint4*)(Vt + vbase + (size_t)row * SEQ + t0 + ch);
        }
        __syncthreads();

        // S = Q K^T (hi/lo), keys nt*16+col, rows quad*4+r
        float sc[4][4];
#pragma unroll
        for (int nt = 0; nt < 4; nt++) {
            bf16x8 bh0 = *(const bf16x8*)(&Kh[nt * 16 + col][quad * 8]);
            bf16x8 bh1 = *(const bf16x8*)(&Kh[nt * 16 + col][32 + quad * 8]);
            bf16x8 bl0 = *(const bf16x8*)(&Kl[nt * 16 + col][quad * 8]);
            bf16x8 bl1 = *(const bf16x8*)(&Kl[nt * 16 + col][32 + quad * 8]);
            f32x4 s = {};
            s = __builtin_amdgcn_mfma_f32_16x16x32_bf16(qh[0], bh0, s, 0, 0, 0);
            s = __builtin_amdgcn_mfma_f32_16x16x32_bf16(qh[1], bh1, s, 0, 0, 0);
            s = __builtin_amdgcn_mfma_f32_16x16x32_bf16(qh[0], bl0, s, 0, 0, 0);
            s = __builtin_amdgcn_mfma_f32_16x16x32_bf16(qh[1], bl1, s, 0, 0, 0);
            s = __builtin_amdgcn_mfma_f32_16x16x32_bf16(ql[0], bh0, s, 0, 0, 0);
            s = __builtin_amdgcn_mfma_f32_16x16x32_bf16(ql[1], bh1, s, 0, 0, 0);
#pragma unroll
            for (int r = 0; r < 4; r++) sc[nt][r] = s[r] * inv_temper;
        }

        // online softmax: row stats via quad shfl_xor reductions
        float tmax[4];
#pragma unroll
        for (int r = 0; r < 4; r++)
            tmax[r] = fmaxf(fmaxf(sc[0][r], sc[1][r]), fmaxf(sc[2][r], sc[3][r]));
#pragma unroll
        for (int mask = 1; mask < 16; mask <<= 1)
#pragma unroll
            for (int r = 0; r < 4; r++)
                tmax[r] = fmaxf(tmax[r], __shfl_xor(tmax[r], mask, 64));

        float alpha[4], tsum[4];
#pragma unroll
        for (int r = 0; r < 4; r++) {
            float mn = fmaxf(mrun[r], tmax[r]);
            alpha[r] = __expf(mrun[r] - mn);
            mrun[r] = mn;
            tsum[r] = 0.f;
        }
#pragma unroll
        for (int nt = 0; nt < 4; nt++)
#pragma unroll
            for (int r = 0; r < 4; r++) {
                float pv = __expf(sc[nt][r] - mrun[r]);
                tsum[r] += pv;
                Pl[w][quad * 4 + r][nt * 16 + col] = f2bf(pv);
            }
#pragma unroll
        for (int mask = 1; mask < 16; mask <<= 1)
#pragma unroll
            for (int r = 0; r < 4; r++)
                tsum[r] += __shfl_xor(tsum[r], mask, 64);
#pragma unroll
        for (int r = 0; r < 4; r++)
            lrun[r] = lrun[r] * alpha[r] + tsum[r];
#pragma unroll
        for (int nt = 0; nt < 4; nt++)
#pragma unroll
            for (int r = 0; r < 4; r++)
                acco[nt][r] *= alpha[r];

        // P is wave-local: no block barrier needed (compiler orders LDS ops)
        union { ulong2 u; bf16x8 v; } a0, a1;
        a0.u.x = *(const ull_t*)(&Pl[w][col][quad * 8]);
        a0.u.y = *(const ull_t*)(&Pl[w][col][quad * 8 + 4]);
        a1.u.x = *(const ull_t*)(&Pl[w][col][32 + quad * 8]);
        a1.u.y = *(const ull_t*)(&Pl[w][col][32 + quad * 8 + 4]);
#pragma unroll
        for (int nt = 0; nt < 4; nt++) {
            bf16x8 bv0 = *(const bf16x8*)(&Vs[nt * 16 + col][quad * 8]);
            bf16x8 bv1 = *(const bf16x8*)(&Vs[nt * 16 + col][32 + quad * 8]);
            acco[nt] = __builtin_amdgcn_mfma_f32_16x16x32_bf16(a0.v, bv0, acco[nt], 0, 0, 0);
            acco[nt] = __builtin_amdgcn_mfma_f32_16x16x32_bf16(a1.v, bv1, acco[nt], 0, 0, 0);
        }
    }

    // epilogue: O[b][row][h*64 + dim], dim = nt*16+col, row = qt*64+w*16+quad*4+r
#pragma unroll
    for (int nt = 0; nt < 4; nt++) {
#pragma unroll
        for (int r = 0; r < 4; r++) {
            int row = qt * 64 + w * 16 + quad * 4 + r;
            O[((size_t)b * SEQ + row) * D_MODEL + h * D_HEAD + nt * 16 + col]
                = acco[nt][r] / lrun[r];
        }
    }
}

// ---------------------------------------------------------------- add + LN
__device__ inline float block_sum_256(float v, float* tmp) {
#pragma unroll
    for (int off = 32; off > 0; off >>= 1) v += __shfl_down(v, off, 64);
    if ((threadIdx.x & 63) == 0) tmp[threadIdx.x >> 6] = v;
    __syncthreads();
    return tmp[0] + tmp[1] + tmp[2] + tmp[3];
}

// Writes fp32 Out AND bf16 OutBf. Safe for Out==R (in-place).
__global__ void add_norm_kernel(const float* __restrict__ A,
                                const float* __restrict__ R,
                                const float* __restrict__ ga,
                                const float* __restrict__ gb,
                                float* __restrict__ Out,
                                ushort_t* __restrict__ OutBf) {
    int tok = blockIdx.x, tid = threadIdx.x;
    __shared__ float t1[4], t2[4];
    size_t base = (size_t)tok * D_MODEL;
    float z0 = A[base + tid]       + R[base + tid];
    float z1 = A[base + tid + 256] + R[base + tid + 256];
    float s = block_sum_256(z0 + z1, t1);
    float mu = s * (1.f / (float)D_MODEL);
    float d0 = z0 - mu, d1 = z1 - mu;
    float ss = block_sum_256(d0 * d0 + d1 * d1, t2);
    float sigma = sqrtf(ss * (1.f / (float)(D_MODEL - 1)));
    float inv = 1.f / (sigma + LN_EPS);
    float r0 = d0 * inv * ga[tid]       + gb[tid];
    float r1 = d1 * inv * ga[tid + 256] + gb[tid + 256];
    Out[base + tid]         = r0;
    Out[base + tid + 256]   = r1;
    OutBf[base + tid]       = f2bf(r0);
    OutBf[base + tid + 256] = f2bf(r1);
}

// ---------------------------------------------------------------- launch
extern "C" void kernel_launch(void* const* d_in, const int* in_sizes, int n_in,
                              void* d_out, int out_size, void* d_ws, size_t ws_size,
                              hipStream_t stream) {
    const float* x     = (const float*)d_in[0];
    const float* pe    = (const float*)d_in[1];
    const float* w_qs  = (const float*)d_in[2];
    const float* w_ks  = (const float*)d_in[3];
    const float* w_vs  = (const float*)d_in[4];
    const float* ln1_a = (const float*)d_in[5];
    const float* ln1_b = (const float*)d_in[6];
    const float* w1    = (const float*)d_in[7];
    const float* b1    = (const float*)d_in[8];
    const float* w2    = (const float*)d_in[9];
    const float* b2    = (const float*)d_in[10];
    const float* ln2_a = (const float*)d_in[11];
    const float* ln2_b = (const float*)d_in[12];
    float* out = (float*)d_out;

    const size_t NXD = (size_t)NTOK * D_MODEL;       // 2M elements
    char* p = (char*)d_ws;
    float*    X    = (float*)p;     p += NXD * 4;                 // 8 MB
    float*    Ob   = (float*)p;     p += NXD * 4;                 // 8 MB
    ushort_t* Xbf  = (ushort_t*)p;  p += NXD * 2;                 // 4 MB
    ushort_t* Qhi  = (ushort_t*)p;  p += NXD * 2;                 // 4 MB
    ushort_t* Qlo  = (ushort_t*)p;  p += NXD * 2;                 // 4 MB
    ushort_t* Khi  = (ushort_t*)p;  p += NXD * 2;                 // 4 MB
    ushort_t* Klo  = (ushort_t*)p;  p += NXD * 2;                 // 4 MB
    ushort_t* Vt   = (ushort_t*)p;  p += NXD * 2;                 // 4 MB
    ushort_t* Wqkv = (ushort_t*)p;  p += (size_t)N_LAYERS * 1536 * 512 * 2;  // 3 MB (hi)
    ushort_t* WqkvL= (ushort_t*)p;  p += (size_t)1536 * 512 * 2;  // 1.5 MB (lo, layer 0)
    ushort_t* W1b  = (ushort_t*)p;  p += (size_t)N_LAYERS * D_INNER * D_MODEL * 2;  // 2 MB
    ushort_t* W2b  = (ushort_t*)p;  /* 2 MB */
    // H (bf16, 8 MB) aliases Qhi+Qlo: Q dead after attention, rewritten next
    // layer's QKV GEMM (which runs after FFN2 consumed H). Stream-ordered safe.
    ushort_t* Hbf  = Qhi;

    add_pos_kernel<<<(int)(NXD / 256), 256, 0, stream>>>(x, pe, X);

    for (int i = 0; i < N_LAYERS; i++) {
        conv_qkvw_kernel<<<1536 * 512 / 256, 256, 0, stream>>>(
            w_qs + (size_t)i * N_HEAD * D_MODEL * D_HEAD,
            w_ks + (size_t)i * N_HEAD * D_MODEL * D_HEAD,
            w_vs + (size_t)i * N_HEAD * D_MODEL * D_HEAD,
            Wqkv + (size_t)i * 1536 * 512,
            (i == 0) ? WqkvL : (ushort_t*)nullptr);
    }
    conv_bf16_kernel<<<(N_LAYERS * D_INNER * D_MODEL) / 256, 256, 0, stream>>>(
        w1, W1b, N_LAYERS * D_INNER * D_MODEL);
    conv_bf16_kernel<<<(N_LAYERS * D_MODEL * D_INNER) / 256, 256, 0, stream>>>(
        w2, W2b, N_LAYERS * D_MODEL * D_INNER);

    for (int i = 0; i < N_LAYERS; i++) {
        // QKV: M=4096, N=1536, K=512 -> scatter to Qhi/Qlo/Khi/Klo/Vt
        if (i == 0) {
            gemm_hilo_kernel<<<dim3(1536 / 64, NTOK / 64), 256, 0, stream>>>(
                X, Wqkv, WqkvL, Qhi, Qlo, Khi, Klo, Vt, NTOK, 1536, D_MODEL);
        } else {
            gemm_kernel<0><<<dim3(1536 / 64, NTOK / 64), 256, 0, stream>>>(
                Xbf, Wqkv + (size_t)i * 1536 * 512, nullptr, nullptr, nullptr,
                Qhi, Qlo, Khi, Klo, Vt, NTOK, 1536, D_MODEL);
        }

        attention_kernel<<<512, 256, 0, stream>>>(Qhi, Qlo, Khi, Klo, Vt, Ob);

        add_norm_kernel<<<NTOK, 256, 0, stream>>>(
            Ob, X, ln1_a + i * D_MODEL, ln1_b + i * D_MODEL, X, Xbf);

        // FFN1: M=4096, N=1024, K=512, bias+relu -> bf16 H (aliases Qhi/Qlo)
        gemm_kernel<1><<<dim3(D_INNER / 64, NTOK / 64), 256, 0, stream>>>(
            Xbf, W1b + (size_t)i * D_INNER * D_MODEL, b1 + (size_t)i * D_INNER,
            nullptr, Hbf, nullptr, nullptr, nullptr, nullptr, nullptr,
            NTOK, D_INNER, D_MODEL);

        // FFN2: M=4096, N=512, K=1024, bias -> fp32 Ob
        gemm_kernel<2><<<dim3(D_MODEL / 64, NTOK / 64), 256, 0, stream>>>(
            Hbf, W2b + (size_t)i * D_MODEL * D_INNER, b2 + (size_t)i * D_MODEL,
            Ob, nullptr, nullptr, nullptr, nullptr, nullptr, nullptr,
            NTOK, D_MODEL, D_INNER);

        float* dst = (i == N_LAYERS - 1) ? out : X;
        add_norm_kernel<<<NTOK, 256, 0, stream>>>(
            Ob, X, ln2_a + i * D_MODEL, ln2_b + i * D_MODEL, dst, Xbf);
    }
}

// Round 10
// 385.392 us; speedup vs baseline: 12.3252x; 1.0074x over previous
//
#include <hip/hip_runtime.h>
#include <math.h>

#define D_MODEL 512
#define SEQ     1024
#define BATCH   4
#define N_LAYERS 2
#define N_HEAD  8
#define D_HEAD  64
#define D_INNER 1024
#define NTOK    (BATCH*SEQ)   // 4096
#define LN_EPS  1e-3f

typedef float f32x4 __attribute__((ext_vector_type(4)));
typedef short bf16x8 __attribute__((ext_vector_type(8)));
typedef unsigned short ushort_t;
typedef unsigned int uint_t;
typedef unsigned long long ull_t;

// fp32 -> bf16 round-to-nearest-even
__device__ inline ushort_t f2bf(float f) {
    uint_t u = __float_as_uint(f);
    u += 0x7FFFu + ((u >> 16) & 1u);
    return (ushort_t)(u >> 16);
}
__device__ inline float bf2f(ushort_t h) {
    return __uint_as_float((uint_t)h << 16);
}

// ---------------------------------------------------------------- add pos enc
// X = x + pe (fp32 residual path); Xrawbf = bf16(x) (layer-1 xW GEMM input)
__global__ void add_pos_kernel(const float* __restrict__ x,
                               const float* __restrict__ pe,
                               float* __restrict__ X,
                               ushort_t* __restrict__ Xrawbf) {
    int idx = blockIdx.x * blockDim.x + threadIdx.x;   // over NTOK*D_MODEL
    int l = (idx / D_MODEL) % SEQ;
    int d = idx % D_MODEL;
    float xv = x[idx];
    X[idx] = xv + pe[l * D_MODEL + d];
    Xrawbf[idx] = f2bf(xv);
}

// ---------------------------------------------------------------- weight conv
__global__ void conv_bf16_kernel(const float* __restrict__ src,
                                 ushort_t* __restrict__ dst, int n) {
    int idx = blockIdx.x * 256 + threadIdx.x;
    if (idx < n) dst[idx] = f2bf(src[idx]);
}

// Pack per-layer QKV weights into Bt layout [1536][512] (hi, optional lo):
// row n: which=n>>9, h=(n>>6)&7, d=n&63 ; Bt[n][k] = W_which[h][k][d]
__global__ void conv_qkvw_kernel(const float* __restrict__ wq,
                                 const float* __restrict__ wk,
                                 const float* __restrict__ wv,
                                 ushort_t* __restrict__ hi,
                                 ushort_t* __restrict__ lo) {
    int idx = blockIdx.x * 256 + threadIdx.x;   // over 1536*512
    int n = idx >> 9, k = idx & 511;
    int which = n >> 9, h = (n >> 6) & 7, d = n & 63;
    const float* W = (which == 0) ? wq : (which == 1) ? wk : wv;
    float v = W[((size_t)h * D_MODEL + k) * D_HEAD + d];
    ushort_t hv = f2bf(v);
    hi[idx] = hv;
    if (lo) lo[idx] = f2bf(v - bf2f(hv));
}

// ---------------------------------------------------------------- QKV scatter
// n in [0,1536): which=n>>9 (0:Q 1:K 2:V), head=(n>>6)&7, d=n&63.
// Optional pew add (layer 1): acc += peW[l][n], broadcast over batch.
// Q,K -> hi/lo bf16 [hb][seq][64]; V -> bf16 transposed [hb][dim][seq].
__device__ inline void qkv_scatter(f32x4 a, int n, int m_base,
                                   const float* __restrict__ pew,
                                   ushort_t* Qhi, ushort_t* Qlo,
                                   ushort_t* Khi, ushort_t* Klo,
                                   ushort_t* Vt) {
    int which = n >> 9, hd = n & 511;
    int head = hd >> 6, d = hd & 63;
    int hb = head * BATCH + (m_base >> 10);
    int l  = m_base & 1023;
    if (pew) {
#pragma unroll
        for (int r = 0; r < 4; r++) a[r] += pew[(size_t)(l + r) * 1536 + n];
    }
    if (which == 2) {
        ushort4 pk = make_ushort4(f2bf(a[0]), f2bf(a[1]), f2bf(a[2]), f2bf(a[3]));
        *(ushort4*)(Vt + ((size_t)hb * D_HEAD + d) * SEQ + l) = pk;
    } else {
        ushort_t* H = (which == 0) ? Qhi : Khi;
        ushort_t* L = (which == 0) ? Qlo : Klo;
#pragma unroll
        for (int r = 0; r < 4; r++) {
            float v = a[r];
            ushort_t hv = f2bf(v);
            size_t off = ((size_t)hb * SEQ + l + r) * D_HEAD + d;
            H[off] = hv;
            L[off] = f2bf(v - bf2f(hv));
        }
    }
}

// ---------------------------------------------------------------- MFMA GEMM
// C[M,N] = A[M,K] @ Bt[N,K]^T ; A,Bt bf16 row-major, acc fp32.
// Block: 256 thr = 4 waves, tile 64x64, wave tile 32x32 (2x2 of 16x16x32).
// MODE 0: (+pew) qkv_scatter  MODE 1: +bias, relu, bf16 out  MODE 2: +bias, fp32 out
template<int MODE>
__global__ __launch_bounds__(256, 2)
void gemm_kernel(const ushort_t* __restrict__ A, const ushort_t* __restrict__ Bt,
                 const float* __restrict__ bias, const float* __restrict__ pew,
                 float* __restrict__ outF, ushort_t* __restrict__ outB,
                 ushort_t* __restrict__ Qhi, ushort_t* __restrict__ Qlo,
                 ushort_t* __restrict__ Khi, ushort_t* __restrict__ Klo,
                 ushort_t* __restrict__ Vt,
                 int M, int N, int K) {
    __shared__ ushort_t As[64][72];   // +8 pad: keeps 16B align, breaks bank alias
    __shared__ ushort_t Bs[64][72];
    const int tid = threadIdx.x;
    const int m0 = blockIdx.y * 64, n0 = blockIdx.x * 64;
    const int w = tid >> 6, lane = tid & 63;
    const int wm = (w >> 1) * 32, wn = (w & 1) * 32;
    const int col = lane & 15, quad = lane >> 4;

    f32x4 acc[2][2] = {};

    for (int k0 = 0; k0 < K; k0 += 64) {
        __syncthreads();
#pragma unroll
        for (int p = 0; p < 2; p++) {
            int idx = p * 256 + tid;          // 512 tasks: 64 rows x 8 chunks
            int row = idx >> 3, ch = (idx & 7) * 8;
            *(uint4*)(&As[row][ch]) =
                *(const uint4*)(A + (size_t)(m0 + row) * K + k0 + ch);
            *(uint4*)(&Bs[row][ch]) =
                *(const uint4*)(Bt + (size_t)(n0 + row) * K + k0 + ch);
        }
        __syncthreads();
#pragma unroll
        for (int ks = 0; ks < 64; ks += 32) {
            bf16x8 af[2], bf[2];
#pragma unroll
            for (int t = 0; t < 2; t++) {
                af[t] = *(const bf16x8*)(&As[wm + t * 16 + col][ks + quad * 8]);
                bf[t] = *(const bf16x8*)(&Bs[wn + t * 16 + col][ks + quad * 8]);
            }
#pragma unroll
            for (int mt = 0; mt < 2; mt++)
#pragma unroll
                for (int nt = 0; nt < 2; nt++)
                    acc[mt][nt] = __builtin_amdgcn_mfma_f32_16x16x32_bf16(
                        af[mt], bf[nt], acc[mt][nt], 0, 0, 0);
        }
    }

#pragma unroll
    for (int mt = 0; mt < 2; mt++) {
#pragma unroll
        for (int nt = 0; nt < 2; nt++) {
            int n = n0 + wn + nt * 16 + col;
            int m_base = m0 + wm + mt * 16 + quad * 4;
            if (MODE == 0) {
                qkv_scatter(acc[mt][nt], n, m_base, pew, Qhi, Qlo, Khi, Klo, Vt);
            } else {
#pragma unroll
                for (int r = 0; r < 4; r++) {
                    int m = m_base + r;
                    float v = acc[mt][nt][r];
                    if (MODE == 1) {
                        float t = fmaxf(v + bias[n], 0.f);
                        outB[(size_t)m * N + n] = f2bf(t);
                    } else {
                        outF[(size_t)m * N + n] = v + bias[n];
                    }
                }
            }
        }
    }
}

// ---------------------------------------------------------------- hi/lo GEMM
// High-precision bf16 GEMM: A fp32 split in-kernel into hi+lo bf16; Bt
// pre-split (hi,lo). acc = Ah*Bh + Ah*Bl + Al*Bh (~1e-5 rel). fp32 out [M][N].
// Used for peW = pos_enc @ Wqkv (M=SEQ=1024).
__global__ __launch_bounds__(256, 2)
void gemm_hilo_kernel(const float* __restrict__ A,
                      const ushort_t* __restrict__ Bh,
                      const ushort_t* __restrict__ Bl,
                      float* __restrict__ outF, int M, int N, int K) {
    __shared__ ushort_t Ash[64][72];
    __shared__ ushort_t Asl[64][72];
    __shared__ ushort_t Bsh[64][72];
    __shared__ ushort_t Bsl[64][72];
    const int tid = threadIdx.x;
    const int m0 = blockIdx.y * 64, n0 = blockIdx.x * 64;
    const int w = tid >> 6, lane = tid & 63;
    const int wm = (w >> 1) * 32, wn = (w & 1) * 32;
    const int col = lane & 15, quad = lane >> 4;

    f32x4 acc[2][2] = {};

    for (int k0 = 0; k0 < K; k0 += 64) {
        __syncthreads();
#pragma unroll
        for (int p = 0; p < 4; p++) {
            int idx = p * 256 + tid;
            int row = idx >> 4, c4 = (idx & 15) * 4;
            float4 v = *(const float4*)(A + (size_t)(m0 + row) * K + k0 + c4);
            ushort_t h0 = f2bf(v.x), h1 = f2bf(v.y), h2 = f2bf(v.z), h3 = f2bf(v.w);
            *(ushort4*)(&Ash[row][c4]) = make_ushort4(h0, h1, h2, h3);
            *(ushort4*)(&Asl[row][c4]) = make_ushort4(
                f2bf(v.x - bf2f(h0)), f2bf(v.y - bf2f(h1)),
                f2bf(v.z - bf2f(h2)), f2bf(v.w - bf2f(h3)));
        }
#pragma unroll
        for (int p = 0; p < 2; p++) {
            int idx = p * 256 + tid;
            int row = idx >> 3, ch = (idx & 7) * 8;
            *(uint4*)(&Bsh[row][ch]) =
                *(const uint4*)(Bh + (size_t)(n0 + row) * K + k0 + ch);
            *(uint4*)(&Bsl[row][ch]) =
                *(const uint4*)(Bl + (size_t)(n0 + row) * K + k0 + ch);
        }
        __syncthreads();
#pragma unroll
        for (int ks = 0; ks < 64; ks += 32) {
            bf16x8 ah[2], al[2], bh[2], bl[2];
#pragma unroll
            for (int t = 0; t < 2; t++) {
                ah[t] = *(const bf16x8*)(&Ash[wm + t * 16 + col][ks + quad * 8]);
                al[t] = *(const bf16x8*)(&Asl[wm + t * 16 + col][ks + quad * 8]);
                bh[t] = *(const bf16x8*)(&Bsh[wn + t * 16 + col][ks + quad * 8]);
                bl[t] = *(const bf16x8*)(&Bsl[wn + t * 16 + col][ks + quad * 8]);
            }
#pragma unroll
            for (int mt = 0; mt < 2; mt++)
#pragma unroll
                for (int nt = 0; nt < 2; nt++) {
                    acc[mt][nt] = __builtin_amdgcn_mfma_f32_16x16x32_bf16(
                        ah[mt], bh[nt], acc[mt][nt], 0, 0, 0);
                    acc[mt][nt] = __builtin_amdgcn_mfma_f32_16x16x32_bf16(
                        ah[mt], bl[nt], acc[mt][nt], 0, 0, 0);
                    acc[mt][nt] = __builtin_amdgcn_mfma_f32_16x16x32_bf16(
                        al[mt], bh[nt], acc[mt][nt], 0, 0, 0);
                }
        }
    }

#pragma unroll
    for (int mt = 0; mt < 2; mt++)
#pragma unroll
        for (int nt = 0; nt < 2; nt++) {
            int n = n0 + wn + nt * 16 + col;
#pragma unroll
            for (int r = 0; r < 4; r++) {
                int m = m0 + wm + mt * 16 + quad * 4 + r;
                outF[(size_t)m * N + n] = acc[mt][nt][r];
            }
        }
}

// ---------------------------------------------------------------- attention
// MFMA flash attention — R6-proven single-buffer structure (2 barriers/tile)
// + __threadfence_block() between P write and P read (fixes latent TBAA UB).
// Block = 64 Q-rows of one (b,h); wave w owns rows w*16..w*16+15.
// XCD swizzle: all 16 Q-tiles of one hb land on one XCD (K/V L2-resident).
__global__ __launch_bounds__(256, 2)
void attention_kernel(const ushort_t* __restrict__ Qhi,
                      const ushort_t* __restrict__ Qlo,
                      const ushort_t* __restrict__ Khi,
                      const ushort_t* __restrict__ Klo,
                      const ushort_t* __restrict__ Vt,
                      float* __restrict__ O) {
    const int bid = blockIdx.x;          // 512
    const int j   = bid >> 3;
    const int hb  = (bid & 7) * 4 + (j >> 4);
    const int qt  = j & 15;
    const int h = hb >> 2, b = hb & 3;
    const int tid = threadIdx.x;
    const int w = tid >> 6, lane = tid & 63;
    const int col = lane & 15, quad = lane >> 4;
    const size_t kbase = (size_t)hb * SEQ * D_HEAD;
    const size_t vbase = (size_t)hb * D_HEAD * SEQ;

    __shared__ ushort_t Kh[64][72];
    __shared__ ushort_t Kl[64][72];
    __shared__ ushort_t Vs[64][72];     // V^T tile [dim][key]
    __shared__ ushort_t Pl[4][16][68];  // per-wave P [qrow][key], stride 68

    // Q fragments hi/lo (A-layout) straight from global
    bf16x8 qh[2], ql[2];
    {
        const ushort_t* qp = Qhi + kbase + (size_t)(qt * 64 + w * 16 + col) * D_HEAD;
        const ushort_t* lp = Qlo + kbase + (size_t)(qt * 64 + w * 16 + col) * D_HEAD;
        qh[0] = *(const bf16x8*)(qp + quad * 8);
        qh[1] = *(const bf16x8*)(qp + 32 + quad * 8);
        ql[0] = *(const bf16x8*)(lp + quad * 8);
        ql[1] = *(const bf16x8*)(lp + 32 + quad * 8);
    }

    f32x4 acco[4] = {};
    float mrun[4], lrun[4];
#pragma unroll
    for (int r = 0; r < 4; r++) { mrun[r] = -1e30f; lrun[r] = 0.f; }
    const float inv_temper = 0.04419417382415922f;  // 1/sqrt(512)

    for (int t0 = 0; t0 < SEQ; t0 += 64) {
        __syncthreads();   // prev tile's reads done before restage
#pragma unroll
        for (int p = 0; p < 2; p++) {
            int idx = p * 256 + tid;          // 512 tasks: 64 rows x 8 chunks
            int row = idx >> 3, ch = (idx & 7) * 8;
            *(uint4*)(&Kh[row][ch]) =
                *(const uint4*)(Khi + kbase + (size_t)(t0 + row) * D_HEAD + ch);
            *(uint4*)(&Kl[row][ch]) =
                *(const uint4*)(Klo + kbase + (size_t)(t0 + row) * D_HEAD + ch);
            *(uint4*)(&Vs[row][ch]) =
                *(const uint4*)(Vt + vbase + (size_t)row * SEQ + t0 + ch);
        }
        __syncthreads();

        // S = Q K^T (hi/lo), keys nt*16+col, rows quad*4+r
        float sc[4][4];
#pragma unroll
        for (int nt = 0; nt < 4; nt++) {
            bf16x8 bh0 = *(const bf16x8*)(&Kh[nt * 16 + col][quad * 8]);
            bf16x8 bh1 = *(const bf16x8*)(&Kh[nt * 16 + col][32 + quad * 8]);
            bf16x8 bl0 = *(const bf16x8*)(&Kl[nt * 16 + col][quad * 8]);
            bf16x8 bl1 = *(const bf16x8*)(&Kl[nt * 16 + col][32 + quad * 8]);
            f32x4 s = {};
            s = __builtin_amdgcn_mfma_f32_16x16x32_bf16(qh[0], bh0, s, 0, 0, 0);
            s = __builtin_amdgcn_mfma_f32_16x16x32_bf16(qh[1], bh1, s, 0, 0, 0);
            s = __builtin_amdgcn_mfma_f32_16x16x32_bf16(qh[0], bl0, s, 0, 0, 0);
            s = __builtin_amdgcn_mfma_f32_16x16x32_bf16(qh[1], bl1, s, 0, 0, 0);
            s = __builtin_amdgcn_mfma_f32_16x16x32_bf16(ql[0], bh0, s, 0, 0, 0);
            s = __builtin_amdgcn_mfma_f32_16x16x32_bf16(ql[1], bh1, s, 0, 0, 0);
#pragma unroll
            for (int r = 0; r < 4; r++) sc[nt][r] = s[r] * inv_temper;
        }

        // online softmax: row stats via quad shfl_xor reductions
        float tmax[4];
#pragma unroll
        for (int r = 0; r < 4; r++)
            tmax[r] = fmaxf(fmaxf(sc[0][r], sc[1][r]), fmaxf(sc[2][r], sc[3][r]));
#pragma unroll
        for (int mask = 1; mask < 16; mask <<= 1)
#pragma unroll
            for (int r = 0; r < 4; r++)
                tmax[r] = fmaxf(tmax[r], __shfl_xor(tmax[r], mask, 64));

        float alpha[4], tsum[4];
#pragma unroll
        for (int r = 0; r < 4; r++) {
            float mn = fmaxf(mrun[r], tmax[r]);
            alpha[r] = __expf(mrun[r] - mn);
            mrun[r] = mn;
            tsum[r] = 0.f;
        }
#pragma unroll
        for (int nt = 0; nt < 4; nt++)
#pragma unroll
            for (int r = 0; r < 4; r++) {
                float pv = __expf(sc[nt][r] - mrun[r]);
                tsum[r] += pv;
                Pl[w][quad * 4 + r][nt * 16 + col] = f2bf(pv);
            }
#pragma unroll
        for (int mask = 1; mask < 16; mask <<= 1)
#pragma unroll
            for (int r = 0; r < 4; r++)
                tsum[r] += __shfl_xor(tsum[r], mask, 64);
#pragma unroll
        for (int r = 0; r < 4; r++)
            lrun[r] = lrun[r] * alpha[r] + tsum[r];
#pragma unroll
        for (int nt = 0; nt < 4; nt++)
#pragma unroll
            for (int r = 0; r < 4; r++)
                acco[nt][r] *= alpha[r];

        // Order the Pl stores before the type-punned reads below (wave-local
        // visibility; also a compiler fence against TBAA reordering).
        __threadfence_block();

        // P (A-layout) and PV
        union { ulong2 u; bf16x8 v; } a0, a1;
        a0.u.x = *(const ull_t*)(&Pl[w][col][quad * 8]);
        a0.u.y = *(const ull_t*)(&Pl[w][col][quad * 8 + 4]);
        a1.u.x = *(const ull_t*)(&Pl[w][col][32 + quad * 8]);
        a1.u.y = *(const ull_t*)(&Pl[w][col][32 + quad * 8 + 4]);
#pragma unroll
        for (int nt = 0; nt < 4; nt++) {
            bf16x8 bv0 = *(const bf16x8*)(&Vs[nt * 16 + col][quad * 8]);
            bf16x8 bv1 = *(const bf16x8*)(&Vs[nt * 16 + col][32 + quad * 8]);
            acco[nt] = __builtin_amdgcn_mfma_f32_16x16x32_bf16(a0.v, bv0, acco[nt], 0, 0, 0);
            acco[nt] = __builtin_amdgcn_mfma_f32_16x16x32_bf16(a1.v, bv1, acco[nt], 0, 0, 0);
        }
    }

    // epilogue: O[b][row][h*64 + dim], dim = nt*16+col, row = qt*64+w*16+quad*4+r
#pragma unroll
    for (int nt = 0; nt < 4; nt++) {
#pragma unroll
        for (int r = 0; r < 4; r++) {
            int row = qt * 64 + w * 16 + quad * 4 + r;
            O[((size_t)b * SEQ + row) * D_MODEL + h * D_HEAD + nt * 16 + col]
                = acco[nt][r] / lrun[r];
        }
    }
}

// ---------------------------------------------------------------- add + LN
__device__ inline float block_sum_256(float v, float* tmp) {
#pragma unroll
    for (int off = 32; off > 0; off >>= 1) v += __shfl_down(v, off, 64);
    if ((threadIdx.x & 63) == 0) tmp[threadIdx.x >> 6] = v;
    __syncthreads();
    return tmp[0] + tmp[1] + tmp[2] + tmp[3];
}

// Writes fp32 Out AND bf16 OutBf. Safe for Out==R (in-place).
__global__ void add_norm_kernel(const float* __restrict__ A,
                                const float* __restrict__ R,
                                const float* __restrict__ ga,
                                const float* __restrict__ gb,
                                float* __restrict__ Out,
                                ushort_t* __restrict__ OutBf) {
    int tok = blockIdx.x, tid = threadIdx.x;
    __shared__ float t1[4], t2[4];
    size_t base = (size_t)tok * D_MODEL;
    float z0 = A[base + tid]       + R[base + tid];
    float z1 = A[base + tid + 256] + R[base + tid + 256];
    float s = block_sum_256(z0 + z1, t1);
    float mu = s * (1.f / (float)D_MODEL);
    float d0 = z0 - mu, d1 = z1 - mu;
    float ss = block_sum_256(d0 * d0 + d1 * d1, t2);
    float sigma = sqrtf(ss * (1.f / (float)(D_MODEL - 1)));
    float inv = 1.f / (sigma + LN_EPS);
    float r0 = d0 * inv * ga[tid]       + gb[tid];
    float r1 = d1 * inv * ga[tid + 256] + gb[tid + 256];
    Out[base + tid]         = r0;
    Out[base + tid + 256]   = r1;
    OutBf[base + tid]       = f2bf(r0);
    OutBf[base + tid + 256] = f2bf(r1);
}

// ---------------------------------------------------------------- launch
extern "C" void kernel_launch(void* const* d_in, const int* in_sizes, int n_in,
                              void* d_out, int out_size, void* d_ws, size_t ws_size,
                              hipStream_t stream) {
    const float* x     = (const float*)d_in[0];
    const float* pe    = (const float*)d_in[1];
    const float* w_qs  = (const float*)d_in[2];
    const float* w_ks  = (const float*)d_in[3];
    const float* w_vs  = (const float*)d_in[4];
    const float* ln1_a = (const float*)d_in[5];
    const float* ln1_b = (const float*)d_in[6];
    const float* w1    = (const float*)d_in[7];
    const float* b1    = (const float*)d_in[8];
    const float* w2    = (const float*)d_in[9];
    const float* b2    = (const float*)d_in[10];
    const float* ln2_a = (const float*)d_in[11];
    const float* ln2_b = (const float*)d_in[12];
    float* out = (float*)d_out;

    const size_t NXD = (size_t)NTOK * D_MODEL;       // 2M elements
    char* p = (char*)d_ws;
    float*    X    = (float*)p;     p += NXD * 4;                 // 8 MB
    float*    Ob   = (float*)p;     p += NXD * 4;                 // 8 MB
    ushort_t* Xbf  = (ushort_t*)p;  p += NXD * 2;                 // 4 MB
    ushort_t* Xraw = (ushort_t*)p;  p += NXD * 2;                 // 4 MB  bf16(x)
    ushort_t* Qhi  = (ushort_t*)p;  p += NXD * 2;                 // 4 MB
    ushort_t* Qlo  = (ushort_t*)p;  p += NXD * 2;                 // 4 MB
    ushort_t* Khi  = (ushort_t*)p;  p += NXD * 2;                 // 4 MB
    ushort_t* Klo  = (ushort_t*)p;  p += NXD * 2;                 // 4 MB
    ushort_t* Vt   = (ushort_t*)p;  p += NXD * 2;                 // 4 MB
    ushort_t* Wqkv = (ushort_t*)p;  p += (size_t)N_LAYERS * 1536 * 512 * 2;  // 3 MB (hi)
    ushort_t* WqkvL= (ushort_t*)p;  p += (size_t)1536 * 512 * 2;  // 1.5 MB (lo, layer 0)
    ushort_t* W1b  = (ushort_t*)p;  p += (size_t)N_LAYERS * D_INNER * D_MODEL * 2;  // 2 MB
    ushort_t* W2b  = (ushort_t*)p;  /* 2 MB */
    // Aliases (stream-ordered safe):
    //  H (bf16, 8 MB) = Qhi+Qlo: Q dead after attention; H consumed by FFN2
    //  before next layer's QKV GEMM rewrites Q.
    //  PEW (fp32 [1024][1536], 6 MB) = Ob: produced+consumed before attention
    //  writes Ob in layer 1; unused afterwards.
    ushort_t* Hbf  = Qhi;
    float*    PEW  = Ob;

    add_pos_kernel<<<(int)(NXD / 256), 256, 0, stream>>>(x, pe, X, Xraw);

    for (int i = 0; i < N_LAYERS; i++) {
        conv_qkvw_kernel<<<1536 * 512 / 256, 256, 0, stream>>>(
            w_qs + (size_t)i * N_HEAD * D_MODEL * D_HEAD,
            w_ks + (size_t)i * N_HEAD * D_MODEL * D_HEAD,
            w_vs + (size_t)i * N_HEAD * D_MODEL * D_HEAD,
            Wqkv + (size_t)i * 1536 * 512,
            (i == 0) ? WqkvL : (ushort_t*)nullptr);
    }
    conv_bf16_kernel<<<(N_LAYERS * D_INNER * D_MODEL) / 256, 256, 0, stream>>>(
        w1, W1b, N_LAYERS * D_INNER * D_MODEL);
    conv_bf16_kernel<<<(N_LAYERS * D_MODEL * D_INNER) / 256, 256, 0, stream>>>(
        w2, W2b, N_LAYERS * D_MODEL * D_INNER);

    for (int i = 0; i < N_LAYERS; i++) {
        if (i == 0) {
            // peW = pe @ Wqkv, fp32-accurate (hi/lo), M=1024 (batch-invariant)
            gemm_hilo_kernel<<<dim3(1536 / 64, SEQ / 64), 256, 0, stream>>>(
                pe, Wqkv, WqkvL, PEW, SEQ, 1536, D_MODEL);
            // QKV = xW (plain bf16) + peW (epilogue add) -> hi/lo scatter
            gemm_kernel<0><<<dim3(1536 / 64, NTOK / 64), 256, 0, stream>>>(
                Xraw, Wqkv, nullptr, PEW, nullptr, nullptr,
                Qhi, Qlo, Khi, Klo, Vt, NTOK, 1536, D_MODEL);
        } else {
            gemm_kernel<0><<<dim3(1536 / 64, NTOK / 64), 256, 0, stream>>>(
                Xbf, Wqkv + (size_t)i * 1536 * 512, nullptr, nullptr, nullptr,
                nullptr, Qhi, Qlo, Khi, Klo, Vt, NTOK, 1536, D_MODEL);
        }

        attention_kernel<<<512, 256, 0, stream>>>(Qhi, Qlo, Khi, Klo, Vt, Ob);

        add_norm_kernel<<<NTOK, 256, 0, stream>>>(
            Ob, X, ln1_a + i * D_MODEL, ln1_b + i * D_MODEL, X, Xbf);

        // FFN1: M=4096, N=1024, K=512, bias+relu -> bf16 H (aliases Qhi/Qlo)
        gemm_kernel<1><<<dim3(D_INNER / 64, NTOK / 64), 256, 0, stream>>>(
            Xbf, W1b + (size_t)i * D_INNER * D_MODEL, b1 + (size_t)i * D_INNER,
            nullptr, nullptr, Hbf, nullptr, nullptr, nullptr, nullptr, nullptr,
            NTOK, D_INNER, D_MODEL);

        // FFN2: M=4096, N=512, K=1024, bias -> fp32 Ob
        gemm_kernel<2><<<dim3(D_MODEL / 64, NTOK / 64), 256, 0, stream>>>(
            Hbf, W2b + (size_t)i * D_MODEL * D_INNER, b2 + (size_t)i * D_MODEL,
            nullptr, Ob, nullptr, nullptr, nullptr, nullptr, nullptr, nullptr,
            NTOK, D_MODEL, D_INNER);

        float* dst = (i == N_LAYERS - 1) ? out : X;
        add_norm_kernel<<<NTOK, 256, 0, stream>>>(
            Ob, X, ln2_a + i * D_MODEL, ln2_b + i * D_MODEL, dst, Xbf);
    }
}